// Round 1
// baseline (4427.544 us; speedup 1.0000x reference)
//
#include <hip/hip_runtime.h>
#include <hip/hip_bf16.h>
#include <math.h>

// ---------------- problem constants ----------------
#define B_    2
#define S_    2048
#define D_    1024
#define DI    2048      // D_INNER
#define NH    32        // NHEADS (mamba)
#define HD    64        // HEADDIM
#define DS    128       // D_STATE
#define CH    64        // CHUNK
#define NC    32        // S_/CH
#define DP    4384      // D_PROJ
#define HATT  16        // attention heads
#define KVH   4         // kv heads
#define RD    16        // rope dims
#define MLP   3072
#define ROWS  (B_*S_)   // 4096

// ---------------- reductions ----------------
__device__ __forceinline__ float waveReduceSum(float v) {
#pragma unroll
  for (int off = 32; off > 0; off >>= 1) v += __shfl_down(v, off, 64);
  return v;
}

template<int NW>
__device__ __forceinline__ float blockReduceSum(float v, float* sh) {
  v = waveReduceSum(v);
  int lane = threadIdx.x & 63, wid = threadIdx.x >> 6;
  if (lane == 0) sh[wid] = v;
  __syncthreads();
  float s = 0.f;
#pragma unroll
  for (int i = 0; i < NW; i++) s += sh[i];
  __syncthreads();
  return s;
}

// ---------------- norm kernels ----------------
__global__ __launch_bounds__(256) void rmsnorm_k(const float* __restrict__ x,
                                                 const float* __restrict__ w,
                                                 float* __restrict__ y, int n) {
  __shared__ float sh[4];
  size_t row = blockIdx.x;
  const float* xr = x + row * n;
  float* yr = y + row * n;
  float ss = 0.f;
  for (int i = threadIdx.x; i < n; i += 256) { float v = xr[i]; ss += v * v; }
  ss = blockReduceSum<4>(ss, sh);
  float inv = rsqrtf(ss / n + 1e-5f);
  for (int i = threadIdx.x; i < n; i += 256) yr[i] = xr[i] * inv * w[i];
}

__global__ __launch_bounds__(256) void layernorm_k(const float* __restrict__ x,
                                                   const float* __restrict__ w,
                                                   const float* __restrict__ b,
                                                   float* __restrict__ y, int n) {
  __shared__ float sh[4];
  size_t row = blockIdx.x;
  const float* xr = x + row * n;
  float* yr = y + row * n;
  float s = 0.f, s2 = 0.f;
  for (int i = threadIdx.x; i < n; i += 256) { float v = xr[i]; s += v; s2 += v * v; }
  s  = blockReduceSum<4>(s,  sh);
  s2 = blockReduceSum<4>(s2, sh);
  float mean = s / n;
  float var  = s2 / n - mean * mean;
  float inv  = rsqrtf(var + 1e-5f);
  for (int i = threadIdx.x; i < n; i += 256)
    yr[i] = (xr[i] - mean) * inv * w[i] + b[i];
}

// ---------------- generic f32 GEMM: C = act(A @ W^T) (+R) ----------------
// A: MxK row-major, W: NxK row-major, C/R: MxN. ACT: 0 none, 1 silu.
template<int ACT>
__global__ __launch_bounds__(256) void gemm_bt(const float* __restrict__ A,
                                               const float* __restrict__ W,
                                               const float* __restrict__ R,
                                               float* __restrict__ C,
                                               int M, int N, int K) {
  __shared__ float As[16][64 + 1];
  __shared__ float Ws[16][64 + 1];
  int bm = blockIdx.y * 64, bn = blockIdx.x * 64;
  int tid = threadIdx.x;
  int tx = tid & 15, ty = tid >> 4;
  float acc[4][4] = {};
  for (int k0 = 0; k0 < K; k0 += 16) {
#pragma unroll
    for (int i = 0; i < 4; i++) {
      int idx = tid + i * 256;
      int m = idx >> 4, k = idx & 15;
      As[k][m] = A[(size_t)(bm + m) * K + k0 + k];
    }
#pragma unroll
    for (int i = 0; i < 4; i++) {
      int idx = tid + i * 256;
      int n = idx >> 4, k = idx & 15;
      int gn = bn + n;
      Ws[k][n] = (gn < N) ? W[(size_t)gn * K + k0 + k] : 0.f;
    }
    __syncthreads();
#pragma unroll
    for (int kk = 0; kk < 16; kk++) {
      float a[4], b[4];
#pragma unroll
      for (int i = 0; i < 4; i++) a[i] = As[kk][ty + i * 16];
#pragma unroll
      for (int j = 0; j < 4; j++) b[j] = Ws[kk][tx + j * 16];
#pragma unroll
      for (int i = 0; i < 4; i++)
#pragma unroll
        for (int j = 0; j < 4; j++) acc[i][j] += a[i] * b[j];
    }
    __syncthreads();
  }
#pragma unroll
  for (int i = 0; i < 4; i++) {
    int gm = bm + ty + i * 16;
#pragma unroll
    for (int j = 0; j < 4; j++) {
      int gn = bn + tx + j * 16;
      if (gn < N) {
        float v = acc[i][j];
        if (ACT == 1) v = v / (1.f + __expf(-v));
        if (R) v += R[(size_t)gm * N + gn];
        C[(size_t)gm * N + gn] = v;
      }
    }
  }
}

// ---------------- SSD prep: dt softplus, per-chunk cumsum, chunk totals ----------------
__global__ __launch_bounds__(64) void ssd_prep(const float* __restrict__ zx,
                                               const float* __restrict__ dt_bias,
                                               const float* __restrict__ A_log,
                                               float* __restrict__ dt_out,
                                               float* __restrict__ acum_out,
                                               float* __restrict__ T_out) {
  int bid = blockIdx.x;               // (b*NC + c)*NH + h
  int h = bid % NH;
  int c = (bid / NH) % NC;
  int b = bid / (NH * NC);
  int l = threadIdx.x;
  size_t row = (size_t)(b * S_ + c * CH + l);
  float raw = zx[row * DP + 2 * DI + 2 * DS + h] + dt_bias[h];
  float dtv = (raw > 20.f) ? raw : log1pf(__expf(raw));
  dt_out[row * NH + h] = dtv;
  float a = -__expf(A_log[h]) * dtv;
  // inclusive prefix sum across the 64-lane wave
  float ps = a;
#pragma unroll
  for (int off = 1; off < 64; off <<= 1) {
    float t = __shfl_up(ps, off, 64);
    if (l >= off) ps += t;
  }
  acum_out[row * NH + h] = ps;
  if (l == 63) T_out[(size_t)(b * NH + h) * NC + c] = ps;
}

// ---------------- B/C rmsnorm ----------------
__global__ __launch_bounds__(128) void bc_norm(const float* __restrict__ zx,
                                               const float* __restrict__ Bw,
                                               const float* __restrict__ Cw,
                                               float* __restrict__ Bn,
                                               float* __restrict__ Cn) {
  __shared__ float shb[2], shc[2];
  size_t row = blockIdx.x;
  int i = threadIdx.x;
  float bv = zx[row * DP + 2 * DI + i];
  float cv = zx[row * DP + 2 * DI + DS + i];
  float sb = waveReduceSum(bv * bv);
  float sc = waveReduceSum(cv * cv);
  int lane = threadIdx.x & 63, wid = threadIdx.x >> 6;
  if (lane == 0) { shb[wid] = sb; shc[wid] = sc; }
  __syncthreads();
  float tb = shb[0] + shb[1];
  float tc = shc[0] + shc[1];
  Bn[row * DS + i] = bv * rsqrtf(tb / DS + 1e-5f) * Bw[i];
  Cn[row * DS + i] = cv * rsqrtf(tc / DS + 1e-5f) * Cw[i];
}

// ---------------- CB[l][s] = dot(C[l], B[s]) per (b,c) (NGROUPS==1) ----------------
__global__ __launch_bounds__(256) void cb_dot(const float* __restrict__ Bn,
                                              const float* __restrict__ Cn,
                                              float* __restrict__ CB) {
  __shared__ float Bs[64][65];
  __shared__ float Cs[64][64];
  int bc = blockIdx.x;
  int b = bc / NC, c = bc % NC;
  int tid = threadIdx.x;
  float acc[16] = {};
  for (int half = 0; half < 2; half++) {
    for (int e = tid; e < 64 * 64; e += 256) {
      int l = e >> 6, n = e & 63;
      size_t row = (size_t)(b * S_ + c * CH + l);
      Bs[l][n] = Bn[row * DS + half * 64 + n];
      Cs[l][n] = Cn[row * DS + half * 64 + n];
    }
    __syncthreads();
#pragma unroll
    for (int j = 0; j < 16; j++) {
      int e = tid + j * 256;
      int l = e >> 6, s = e & 63;
      float d = acc[j];
      for (int n = 0; n < 64; n++) d += Cs[l][n] * Bs[s][n];
      acc[j] = d;
    }
    __syncthreads();
  }
#pragma unroll
  for (int j = 0; j < 16; j++) CB[(size_t)bc * 4096 + tid + j * 256] = acc[j];
}

// ---------------- Y_diag per (b,c,h) ----------------
__global__ __launch_bounds__(256) void ssd_ydiag(const float* __restrict__ zx,
                                                 const float* __restrict__ CB,
                                                 const float* __restrict__ dt,
                                                 const float* __restrict__ acum,
                                                 float* __restrict__ y) {
  __shared__ float Gs[64][64];
  __shared__ float Xs[64][64];
  __shared__ float ac[64];
  int bid = blockIdx.x;
  int h = bid % NH;
  int c = (bid / NH) % NC;
  int b = bid / (NH * NC);
  int tid = threadIdx.x;
  size_t row0 = (size_t)(b * S_ + c * CH);
  int bc = b * NC + c;
  if (tid < CH) ac[tid] = acum[(row0 + tid) * NH + h];
  for (int e = tid; e < 4096; e += 256) (&Gs[0][0])[e] = CB[(size_t)bc * 4096 + e];
  for (int e = tid; e < CH * HD; e += 256) {
    int l = e >> 6, p = e & 63;
    Xs[l][p] = zx[(row0 + l) * DP + DI + h * HD + p] * dt[(row0 + l) * NH + h];
  }
  __syncthreads();
  for (int e = tid; e < 4096; e += 256) {
    int l = e >> 6, s = e & 63;
    float g = 0.f;
    if (l >= s) g = Gs[l][s] * __expf(ac[l] - ac[s]);
    Gs[l][s] = g;
  }
  __syncthreads();
#pragma unroll
  for (int j = 0; j < 16; j++) {
    int e = tid + j * 256;
    int l = e >> 6, p = e & 63;
    float accv = 0.f;
    for (int s = 0; s <= l; s++) accv += Gs[l][s] * Xs[s][p];
    y[((row0 + l) * NH + h) * HD + p] = accv;
  }
}

// ---------------- chunk states per (b,c,h) ----------------
__global__ __launch_bounds__(256) void ssd_states(const float* __restrict__ zx,
                                                  const float* __restrict__ Bn,
                                                  const float* __restrict__ dt,
                                                  const float* __restrict__ acum,
                                                  float* __restrict__ states) {
  __shared__ float Bs[64][129];
  __shared__ float Xs[64][64];
  __shared__ float dec[64];
  int bid = blockIdx.x;
  int h = bid % NH;
  int c = (bid / NH) % NC;
  int b = bid / (NH * NC);
  int tid = threadIdx.x;
  size_t row0 = (size_t)(b * S_ + c * CH);
  if (tid < CH) {
    float a63 = acum[(row0 + CH - 1) * NH + h];
    float as  = acum[(row0 + tid) * NH + h];
    dec[tid] = __expf(a63 - as);
  }
  for (int e = tid; e < CH * DS; e += 256) {
    int l = e >> 7, n = e & 127;
    Bs[l][n] = Bn[(row0 + l) * DS + n];
  }
  for (int e = tid; e < CH * HD; e += 256) {
    int l = e >> 6, p = e & 63;
    Xs[l][p] = zx[(row0 + l) * DP + DI + h * HD + p] * dt[(row0 + l) * NH + h];
  }
  __syncthreads();
  for (int e = tid; e < HD * DS; e += 256) {
    int p = e >> 7, n = e & 127;
    float accv = 0.f;
#pragma unroll 4
    for (int s = 0; s < CH; s++) accv += dec[s] * Xs[s][p] * Bs[s][n];
    states[(size_t)bid * (HD * DS) + e] = accv;
  }
}

// ---------------- inter-chunk scan (in place): N(c) replaces states(c) ----------------
__global__ __launch_bounds__(256) void ssd_scan(float* __restrict__ states,
                                                const float* __restrict__ T) {
  __shared__ float eT[NC];
  int part = blockIdx.x & 7;          // 8 parts of 1024 elems
  int bh = blockIdx.x >> 3;
  int b = bh / NH, h = bh % NH;
  if (threadIdx.x < NC) eT[threadIdx.x] = __expf(T[(size_t)(b * NH + h) * NC + threadIdx.x]);
  __syncthreads();
  const size_t cstride = (size_t)NH * HD * DS;
  size_t base = ((size_t)b * NC * NH + h) * (HD * DS);
#pragma unroll
  for (int j = 0; j < 4; j++) {
    int e = part * 1024 + threadIdx.x + j * 256;
    float carry = 0.f;
    size_t idx = base + e;
    for (int c = 0; c < NC; c++) {
      float sv = states[idx];
      states[idx] = carry;
      carry = sv + eT[c] * carry;
      idx += cstride;
    }
  }
}

// ---------------- Y_off + D skip + silu(z) gating per (b,c,h) ----------------
__global__ __launch_bounds__(256) void ssd_yoff(const float* __restrict__ zx,
                                                const float* __restrict__ Cn,
                                                const float* __restrict__ acum,
                                                const float* __restrict__ nstates,
                                                const float* __restrict__ Dp,
                                                float* __restrict__ y) {
  __shared__ float Cs[64][64];
  __shared__ float Ns[64][65];
  __shared__ float ac[64];
  int bid = blockIdx.x;
  int h = bid % NH;
  int c = (bid / NH) % NC;
  int b = bid / (NH * NC);
  int tid = threadIdx.x;
  size_t row0 = (size_t)(b * S_ + c * CH);
  if (tid < CH) ac[tid] = acum[(row0 + tid) * NH + h];
  float acc[16] = {};
  for (int half = 0; half < 2; half++) {
    for (int e = tid; e < 64 * 64; e += 256) {
      int l = e >> 6, n = e & 63;
      Cs[l][n] = Cn[(row0 + l) * DS + half * 64 + n];
      Ns[l][n] = nstates[(size_t)bid * (HD * DS) + (size_t)l * DS + half * 64 + n];
    }
    __syncthreads();
#pragma unroll
    for (int j = 0; j < 16; j++) {
      int e = tid + j * 256;
      int l = e >> 6, p = e & 63;
      float d = acc[j];
      for (int n = 0; n < 64; n++) d += Cs[l][n] * Ns[p][n];
      acc[j] = d;
    }
    __syncthreads();
  }
#pragma unroll
  for (int j = 0; j < 16; j++) {
    int e = tid + j * 256;
    int l = e >> 6, p = e & 63;
    size_t row = row0 + l;
    size_t yi = (row * NH + h) * HD + p;
    float yv = y[yi] + acc[j] * __expf(ac[l]);
    float xs = zx[row * DP + DI + h * HD + p];
    yv += xs * Dp[h];
    float z = zx[row * DP + h * HD + p];
    yv *= z / (1.f + __expf(-z));
    y[yi] = yv;
  }
}

// ---------------- q/k rmsnorm + rope + gain ----------------
__global__ __launch_bounds__(64) void qk_prep(float* __restrict__ q,
                                              float* __restrict__ k,
                                              const float* __restrict__ q_gain) {
  int bid = blockIdx.x;
  int hh = bid % (HATT + KVH);
  size_t row = bid / (HATT + KVH);
  int s = (int)(row % S_);
  int d = threadIdx.x;
  bool isq = hh < HATT;
  float* vec = isq ? (q + row * (HATT * HD) + hh * HD)
                   : (k + row * (KVH * HD) + (hh - HATT) * HD);
  float v = vec[d];
  float ss = v * v;
#pragma unroll
  for (int off = 32; off > 0; off >>= 1) ss += __shfl_xor(ss, off, 64);
  v *= rsqrtf(ss / 64.f + 1.1920929e-7f);
  float res = v;
  if (d < RD) {
    int i = d & 7;
    float inv = __expf(-(float)i * (0.125f * 9.210340371976184f)); // 10000^(-i/8)
    float ang = (float)s * inv;
    float cs = cosf(ang), sn = sinf(ang);
    float other = __shfl_xor(v, 8, 64);
    res = (d < 8) ? (v * cs + other * sn) : (v * cs - other * sn);
  }
  if (isq) res *= q_gain[hh];
  vec[d] = res;
}

// ---------------- flash-style causal attention ----------------
__global__ __launch_bounds__(256) void attn_k(const float* __restrict__ q,
                                              const float* __restrict__ k,
                                              const float* __restrict__ v,
                                              float* __restrict__ o) {
  __shared__ float Qs[64][65];
  __shared__ float Ks[32][64];
  __shared__ float Vs[32][64];
  __shared__ float Ps[64][33];
  __shared__ float redm[64][4];
  __shared__ float redsum[64][4];
  int qt = blockIdx.x, h = blockIdx.y, b = blockIdx.z;
  int kvh = h >> 2;
  int tid = threadIdx.x;
  int l = tid & 63, cg = tid >> 6;
  for (int e = tid; e < 64 * 64; e += 256) {
    int r = e >> 6, d = e & 63;
    Qs[r][d] = q[((size_t)b * S_ + qt * 64 + r) * (HATT * HD) + h * HD + d];
  }
  float m = -1e30f, lsum = 0.f;
  float oa[16];
#pragma unroll
  for (int i = 0; i < 16; i++) oa[i] = 0.f;
  int qpos = qt * 64 + l;
  int nkt = 2 * qt + 2;
  for (int kt = 0; kt < nkt; kt++) {
    __syncthreads();   // also ensures Qs ready on first iteration
    for (int e = tid; e < 32 * 64; e += 256) {
      int r = e >> 6, d = e & 63;
      size_t row = (size_t)b * S_ + kt * 32 + r;
      Ks[r][d] = k[row * (KVH * HD) + kvh * HD + d];
      Vs[r][d] = v[row * (KVH * HD) + kvh * HD + d];
    }
    __syncthreads();
    float sv[8], lm = -1e30f;
#pragma unroll
    for (int jj = 0; jj < 8; jj++) {
      int j = cg * 8 + jj;
      float dacc = 0.f;
      for (int dd = 0; dd < 64; dd++) dacc += Qs[l][dd] * Ks[j][dd];
      dacc *= 0.125f;
      if (kt * 32 + j > qpos) dacc = -1e30f;
      sv[jj] = dacc;
      lm = fmaxf(lm, dacc);
    }
    redm[l][cg] = lm;
    __syncthreads();
    float mnew = fmaxf(fmaxf(redm[l][0], redm[l][1]), fmaxf(redm[l][2], redm[l][3]));
    mnew = fmaxf(m, mnew);
    float ls = 0.f;
#pragma unroll
    for (int jj = 0; jj < 8; jj++) {
      float p = __expf(sv[jj] - mnew);
      Ps[l][cg * 8 + jj] = p;
      ls += p;
    }
    redsum[l][cg] = ls;
    __syncthreads();
    float rs = redsum[l][0] + redsum[l][1] + redsum[l][2] + redsum[l][3];
    float alpha = __expf(m - mnew);
    lsum = lsum * alpha + rs;
    m = mnew;
#pragma unroll
    for (int i = 0; i < 16; i++) oa[i] *= alpha;
    for (int j = 0; j < 32; j++) {
      float pv = Ps[l][j];
#pragma unroll
      for (int i = 0; i < 16; i++) oa[i] += pv * Vs[j][cg * 16 + i];
    }
  }
  float inv = 1.f / lsum;
#pragma unroll
  for (int i = 0; i < 16; i++)
    o[((size_t)b * S_ + qt * 64 + l) * (HATT * HD) + h * HD + cg * 16 + i] = oa[i] * inv;
}

// ---------------- workspace layout (floats) ----------------
constexpr size_t SZ_H   = (size_t)ROWS * D_;            // 4,194,304
constexpr size_t SZ_Z   = (size_t)ROWS * DP;            // 17,956,864
constexpr size_t OFF_H  = 0;
constexpr size_t OFF_Z  = OFF_H + SZ_H;
constexpr size_t OFF_DT = OFF_Z + SZ_Z;
constexpr size_t OFF_AC = OFF_DT + (size_t)ROWS * NH;
constexpr size_t OFF_T  = OFF_AC + (size_t)ROWS * NH;
constexpr size_t OFF_BN = OFF_T + (size_t)B_ * NH * NC;
constexpr size_t OFF_CN = OFF_BN + (size_t)ROWS * DS;
constexpr size_t OFF_CB = OFF_CN + (size_t)ROWS * DS;
constexpr size_t OFF_ST = OFF_CB + (size_t)B_ * NC * CH * CH;
constexpr size_t SZ_ST  = (size_t)B_ * NC * NH * HD * DS;  // 16,777,216
constexpr size_t OFF_Y  = OFF_ST + SZ_ST;
constexpr size_t OFF_X1 = OFF_Y + (size_t)ROWS * DI;
// attention-phase aliases
constexpr size_t OFF_Q  = OFF_Z;
constexpr size_t OFF_K  = OFF_Q + (size_t)ROWS * (HATT * HD);
constexpr size_t OFF_V  = OFF_K + (size_t)ROWS * (KVH * HD);
constexpr size_t OFF_Y2 = OFF_V + (size_t)ROWS * (KVH * HD);
constexpr size_t OFF_X2 = OFF_ST;                        // states dead after yoff
constexpr size_t OFF_ML = OFF_ST + SZ_H;                 // 12,582,912 fits in states region

extern "C" void kernel_launch(void* const* d_in, const int* in_sizes, int n_in,
                              void* d_out, int out_size, void* d_ws, size_t ws_size,
                              hipStream_t stream) {
  (void)in_sizes; (void)n_in; (void)out_size; (void)ws_size;
  const float* x        = (const float*)d_in[0];
  const float* mnorm_w  = (const float*)d_in[1];
  const float* in_w     = (const float*)d_in[2];
  const float* out_w    = (const float*)d_in[3];
  const float* Dp       = (const float*)d_in[4];
  const float* dt_bias  = (const float*)d_in[5];
  const float* A_log    = (const float*)d_in[6];
  const float* Bn_w     = (const float*)d_in[7];
  const float* Cn_w     = (const float*)d_in[8];
  const float* ln1_w    = (const float*)d_in[9];
  const float* ln1_b    = (const float*)d_in[10];
  const float* cq_w     = (const float*)d_in[11];
  const float* ck_w     = (const float*)d_in[12];
  const float* cv_w     = (const float*)d_in[13];
  const float* cproj_w  = (const float*)d_in[14];
  const float* q_gain   = (const float*)d_in[15];
  const float* ln2_w    = (const float*)d_in[16];
  const float* ln2_b    = (const float*)d_in[17];
  const float* fc_w     = (const float*)d_in[18];
  const float* proj_w   = (const float*)d_in[19];
  float* out = (float*)d_out;
  float* ws = (float*)d_ws;

  float* h    = ws + OFF_H;
  float* zx   = ws + OFF_Z;
  float* dt   = ws + OFF_DT;
  float* acum = ws + OFF_AC;
  float* Tb   = ws + OFF_T;
  float* Bn   = ws + OFF_BN;
  float* Cn   = ws + OFF_CN;
  float* CB   = ws + OFF_CB;
  float* st   = ws + OFF_ST;
  float* yb   = ws + OFF_Y;
  float* x1   = ws + OFF_X1;
  float* qb   = ws + OFF_Q;
  float* kb   = ws + OFF_K;
  float* vb   = ws + OFF_V;
  float* y2   = ws + OFF_Y2;
  float* x2   = ws + OFF_X2;
  float* mlp  = ws + OFF_ML;

  // ---- mamba block ----
  rmsnorm_k<<<ROWS, 256, 0, stream>>>(x, mnorm_w, h, D_);
  gemm_bt<0><<<dim3((DP + 63) / 64, ROWS / 64), 256, 0, stream>>>(h, in_w, nullptr, zx, ROWS, DP, D_);
  ssd_prep<<<B_ * NC * NH, 64, 0, stream>>>(zx, dt_bias, A_log, dt, acum, Tb);
  bc_norm<<<ROWS, 128, 0, stream>>>(zx, Bn_w, Cn_w, Bn, Cn);
  cb_dot<<<B_ * NC, 256, 0, stream>>>(Bn, Cn, CB);
  ssd_ydiag<<<B_ * NC * NH, 256, 0, stream>>>(zx, CB, dt, acum, yb);
  ssd_states<<<B_ * NC * NH, 256, 0, stream>>>(zx, Bn, dt, acum, st);
  ssd_scan<<<B_ * NH * 8, 256, 0, stream>>>(st, Tb);
  ssd_yoff<<<B_ * NC * NH, 256, 0, stream>>>(zx, Cn, acum, st, Dp, yb);
  gemm_bt<0><<<dim3(D_ / 64, ROWS / 64), 256, 0, stream>>>(yb, out_w, x, x1, ROWS, D_, DI);

  // ---- attention block ----
  layernorm_k<<<ROWS, 256, 0, stream>>>(x1, ln1_w, ln1_b, h, D_);
  gemm_bt<0><<<dim3(D_ / 64, ROWS / 64), 256, 0, stream>>>(h, cq_w, nullptr, qb, ROWS, D_, D_);
  gemm_bt<0><<<dim3((KVH * HD) / 64, ROWS / 64), 256, 0, stream>>>(h, ck_w, nullptr, kb, ROWS, KVH * HD, D_);
  gemm_bt<0><<<dim3((KVH * HD) / 64, ROWS / 64), 256, 0, stream>>>(h, cv_w, nullptr, vb, ROWS, KVH * HD, D_);
  qk_prep<<<ROWS * (HATT + KVH), 64, 0, stream>>>(qb, kb, q_gain);
  attn_k<<<dim3(S_ / 64, HATT, B_), 256, 0, stream>>>(qb, kb, vb, y2);
  gemm_bt<0><<<dim3(D_ / 64, ROWS / 64), 256, 0, stream>>>(y2, cproj_w, x1, x2, ROWS, D_, D_);

  // ---- MLP ----
  layernorm_k<<<ROWS, 256, 0, stream>>>(x2, ln2_w, ln2_b, h, D_);
  gemm_bt<1><<<dim3(MLP / 64, ROWS / 64), 256, 0, stream>>>(h, fc_w, nullptr, mlp, ROWS, MLP, D_);
  gemm_bt<0><<<dim3(D_ / 64, ROWS / 64), 256, 0, stream>>>(mlp, proj_w, x2, out, ROWS, D_, MLP);
}

// Round 2
// 1109.993 us; speedup vs baseline: 3.9888x; 3.9888x over previous
//
#include <hip/hip_runtime.h>
#include <hip/hip_bf16.h>
#include <math.h>

// ---------------- problem constants ----------------
#define B_    2
#define S_    2048
#define D_    1024
#define DI    2048      // D_INNER
#define NH    32        // NHEADS (mamba)
#define HD    64        // HEADDIM
#define DS    128       // D_STATE
#define CH    64        // CHUNK
#define NC    32        // S_/CH
#define DP    4384      // D_PROJ
#define HATT  16        // attention heads
#define KVH   4         // kv heads
#define RD    16        // rope dims
#define MLP   3072
#define ROWS  (B_*S_)   // 4096

typedef __bf16 bf16;
typedef __bf16 bf16x8 __attribute__((ext_vector_type(8)));
typedef __bf16 bf16x4 __attribute__((ext_vector_type(4)));
typedef float  f32x4  __attribute__((ext_vector_type(4)));

__device__ __forceinline__ void async_copy16(const void* g, void* l) {
  __builtin_amdgcn_global_load_lds(
      (const __attribute__((address_space(1))) unsigned int*)g,
      (__attribute__((address_space(3))) unsigned int*)l, 16, 0, 0);
}

// ---------------- reductions ----------------
__device__ __forceinline__ float waveReduceSum(float v) {
#pragma unroll
  for (int off = 32; off > 0; off >>= 1) v += __shfl_down(v, off, 64);
  return v;
}

template<int NW>
__device__ __forceinline__ float blockReduceSum(float v, float* sh) {
  v = waveReduceSum(v);
  int lane = threadIdx.x & 63, wid = threadIdx.x >> 6;
  if (lane == 0) sh[wid] = v;
  __syncthreads();
  float s = 0.f;
#pragma unroll
  for (int i = 0; i < NW; i++) s += sh[i];
  __syncthreads();
  return s;
}

// ---------------- weight cast f32 -> bf16 (with trailing zero pad) ----------------
__global__ __launch_bounds__(256) void castw(const float* __restrict__ src,
                                             bf16* __restrict__ dst,
                                             int n_valid, int n_total) {
  int i = (blockIdx.x * 256 + threadIdx.x) * 4;
  if (i >= n_total) return;
  float4 v = {0.f, 0.f, 0.f, 0.f};
  if (i < n_valid) v = *(const float4*)(src + i);
  bf16x4 o;
  o[0] = (bf16)v.x; o[1] = (bf16)v.y; o[2] = (bf16)v.z; o[3] = (bf16)v.w;
  *(bf16x4*)(dst + i) = o;
}

// ---------------- norm kernels (f32 in, bf16 out) ----------------
__global__ __launch_bounds__(256) void rmsnorm_k(const float* __restrict__ x,
                                                 const float* __restrict__ w,
                                                 bf16* __restrict__ y, int n) {
  __shared__ float sh[4];
  size_t row = blockIdx.x;
  const float* xr = x + row * n;
  bf16* yr = y + row * n;
  float ss = 0.f;
  for (int i = threadIdx.x; i < n; i += 256) { float v = xr[i]; ss += v * v; }
  ss = blockReduceSum<4>(ss, sh);
  float inv = rsqrtf(ss / n + 1e-5f);
  for (int i = threadIdx.x; i < n; i += 256) yr[i] = (bf16)(xr[i] * inv * w[i]);
}

__global__ __launch_bounds__(256) void layernorm_k(const float* __restrict__ x,
                                                   const float* __restrict__ w,
                                                   const float* __restrict__ b,
                                                   bf16* __restrict__ y, int n) {
  __shared__ float sh[4];
  size_t row = blockIdx.x;
  const float* xr = x + row * n;
  bf16* yr = y + row * n;
  float s = 0.f, s2 = 0.f;
  for (int i = threadIdx.x; i < n; i += 256) { float v = xr[i]; s += v; s2 += v * v; }
  s  = blockReduceSum<4>(s,  sh);
  s2 = blockReduceSum<4>(s2, sh);
  float mean = s / n;
  float var  = s2 / n - mean * mean;
  float inv  = rsqrtf(var + 1e-5f);
  for (int i = threadIdx.x; i < n; i += 256)
    yr[i] = (bf16)((xr[i] - mean) * inv * w[i] + b[i]);
}

// ---------------- bf16 MFMA GEMM: C = act(A @ W^T) (+R) ----------------
// A: MxK bf16 row-major, W: (Npad)xK bf16 row-major (rows >= N zero-padded),
// R: MxN f32 or null, C: MxN (OT = float or bf16). ACT: 0 none, 1 silu.
// Tile 128x128, BK=32, 256 threads (4 waves, 2x2 of 64x64 each).
template<int ACT, typename OT>
__global__ __launch_bounds__(256) void gemm_mfma(const bf16* __restrict__ A,
                                                 const bf16* __restrict__ W,
                                                 const float* __restrict__ R,
                                                 OT* __restrict__ C,
                                                 int M, int N, int K) {
  __shared__ bf16 As[128 * 32];
  __shared__ bf16 Ws[128 * 32];
  int tid = threadIdx.x, lane = tid & 63, wave = tid >> 6;
  int bm = blockIdx.y * 128, bn = blockIdx.x * 128;
  // staging: segment (wave,t) = rows [(wave*2+t)*16, +16); lane covers row lane/4, kchunk lane%4
  const bf16* gA0 = A + (size_t)(bm + wave * 32 + (lane >> 2)) * K + (lane & 3) * 8;
  const bf16* gA1 = gA0 + (size_t)16 * K;
  const bf16* gW0 = W + (size_t)(bn + wave * 32 + (lane >> 2)) * K + (lane & 3) * 8;
  const bf16* gW1 = gW0 + (size_t)16 * K;
  bf16* lA0 = As + wave * 32 * 32;
  bf16* lA1 = lA0 + 16 * 32;
  bf16* lW0 = Ws + wave * 32 * 32;
  bf16* lW1 = lW0 + 16 * 32;
  int fr = lane & 15, fq = lane >> 4;
  int wm = wave >> 1, wn = wave & 1;
  const bf16* pA = As + (wm * 64 + fr) * 32 + fq * 8;
  const bf16* pW = Ws + (wn * 64 + fr) * 32 + fq * 8;
  f32x4 acc[4][4] = {};
  for (int k0 = 0; k0 < K; k0 += 32) {
    async_copy16(gA0, lA0);
    async_copy16(gA1, lA1);
    async_copy16(gW0, lW0);
    async_copy16(gW1, lW1);
    gA0 += 32; gA1 += 32; gW0 += 32; gW1 += 32;
    __syncthreads();
    bf16x8 af[4], bfr[4];
#pragma unroll
    for (int mi = 0; mi < 4; mi++) af[mi] = *(const bf16x8*)(pA + mi * 16 * 32);
#pragma unroll
    for (int ni = 0; ni < 4; ni++) bfr[ni] = *(const bf16x8*)(pW + ni * 16 * 32);
#pragma unroll
    for (int mi = 0; mi < 4; mi++)
#pragma unroll
      for (int ni = 0; ni < 4; ni++)
        acc[mi][ni] = __builtin_amdgcn_mfma_f32_16x16x32_bf16(af[mi], bfr[ni], acc[mi][ni], 0, 0, 0);
    __syncthreads();
  }
#pragma unroll
  for (int mi = 0; mi < 4; mi++) {
    int row = bm + wm * 64 + mi * 16 + fq * 4;
#pragma unroll
    for (int ni = 0; ni < 4; ni++) {
      int col = bn + wn * 64 + ni * 16 + fr;
      if (col < N) {
#pragma unroll
        for (int r = 0; r < 4; r++) {
          float v = acc[mi][ni][r];
          if (ACT == 1) v = v / (1.f + __expf(-v));
          if (R) v += R[(size_t)(row + r) * N + col];
          C[(size_t)(row + r) * N + col] = (OT)v;
        }
      }
    }
  }
}

// ---------------- SSD prep: dt softplus, per-chunk cumsum, chunk totals ----------------
__global__ __launch_bounds__(64) void ssd_prep(const bf16* __restrict__ zx,
                                               const float* __restrict__ dt_bias,
                                               const float* __restrict__ A_log,
                                               float* __restrict__ dt_out,
                                               float* __restrict__ acum_out,
                                               float* __restrict__ T_out) {
  int bid = blockIdx.x;               // (b*NC + c)*NH + h
  int h = bid % NH;
  int c = (bid / NH) % NC;
  int b = bid / (NH * NC);
  int l = threadIdx.x;
  size_t row = (size_t)(b * S_ + c * CH + l);
  float raw = (float)zx[row * DP + 2 * DI + 2 * DS + h] + dt_bias[h];
  float dtv = (raw > 20.f) ? raw : log1pf(__expf(raw));
  dt_out[row * NH + h] = dtv;
  float a = -__expf(A_log[h]) * dtv;
  float ps = a;
#pragma unroll
  for (int off = 1; off < 64; off <<= 1) {
    float t = __shfl_up(ps, off, 64);
    if (l >= off) ps += t;
  }
  acum_out[row * NH + h] = ps;
  if (l == 63) T_out[(size_t)(b * NH + h) * NC + c] = ps;
}

// ---------------- B/C rmsnorm ----------------
__global__ __launch_bounds__(128) void bc_norm(const bf16* __restrict__ zx,
                                               const float* __restrict__ Bw,
                                               const float* __restrict__ Cw,
                                               float* __restrict__ Bn,
                                               float* __restrict__ Cn) {
  __shared__ float shb[2], shc[2];
  size_t row = blockIdx.x;
  int i = threadIdx.x;
  float bv = (float)zx[row * DP + 2 * DI + i];
  float cv = (float)zx[row * DP + 2 * DI + DS + i];
  float sb = waveReduceSum(bv * bv);
  float sc = waveReduceSum(cv * cv);
  int lane = threadIdx.x & 63, wid = threadIdx.x >> 6;
  if (lane == 0) { shb[wid] = sb; shc[wid] = sc; }
  __syncthreads();
  float tb = shb[0] + shb[1];
  float tc = shc[0] + shc[1];
  Bn[row * DS + i] = bv * rsqrtf(tb / DS + 1e-5f) * Bw[i];
  Cn[row * DS + i] = cv * rsqrtf(tc / DS + 1e-5f) * Cw[i];
}

// ---------------- CB[l][s] = dot(C[l], B[s]) per (b,c) ----------------
__global__ __launch_bounds__(256) void cb_dot(const float* __restrict__ Bn,
                                              const float* __restrict__ Cn,
                                              float* __restrict__ CB) {
  __shared__ float Bs[64][65];
  __shared__ float Cs[64][64];
  int bc = blockIdx.x;
  int b = bc / NC, c = bc % NC;
  int tid = threadIdx.x;
  float acc[16] = {};
  for (int half = 0; half < 2; half++) {
    for (int e = tid; e < 64 * 64; e += 256) {
      int l = e >> 6, n = e & 63;
      size_t row = (size_t)(b * S_ + c * CH + l);
      Bs[l][n] = Bn[row * DS + half * 64 + n];
      Cs[l][n] = Cn[row * DS + half * 64 + n];
    }
    __syncthreads();
#pragma unroll
    for (int j = 0; j < 16; j++) {
      int e = tid + j * 256;
      int l = e >> 6, s = e & 63;
      float d = acc[j];
      for (int n = 0; n < 64; n++) d += Cs[l][n] * Bs[s][n];
      acc[j] = d;
    }
    __syncthreads();
  }
#pragma unroll
  for (int j = 0; j < 16; j++) CB[(size_t)bc * 4096 + tid + j * 256] = acc[j];
}

// ---------------- Y_diag per (b,c,h) ----------------
__global__ __launch_bounds__(256) void ssd_ydiag(const bf16* __restrict__ zx,
                                                 const float* __restrict__ CB,
                                                 const float* __restrict__ dt,
                                                 const float* __restrict__ acum,
                                                 float* __restrict__ y) {
  __shared__ float Gs[64][64];
  __shared__ float Xs[64][64];
  __shared__ float ac[64];
  int bid = blockIdx.x;
  int h = bid % NH;
  int c = (bid / NH) % NC;
  int b = bid / (NH * NC);
  int tid = threadIdx.x;
  size_t row0 = (size_t)(b * S_ + c * CH);
  int bc = b * NC + c;
  if (tid < CH) ac[tid] = acum[(row0 + tid) * NH + h];
  for (int e = tid; e < 4096; e += 256) (&Gs[0][0])[e] = CB[(size_t)bc * 4096 + e];
  for (int e = tid; e < CH * HD; e += 256) {
    int l = e >> 6, p = e & 63;
    Xs[l][p] = (float)zx[(row0 + l) * DP + DI + h * HD + p] * dt[(row0 + l) * NH + h];
  }
  __syncthreads();
  for (int e = tid; e < 4096; e += 256) {
    int l = e >> 6, s = e & 63;
    float g = 0.f;
    if (l >= s) g = Gs[l][s] * __expf(ac[l] - ac[s]);
    Gs[l][s] = g;
  }
  __syncthreads();
#pragma unroll
  for (int j = 0; j < 16; j++) {
    int e = tid + j * 256;
    int l = e >> 6, p = e & 63;
    float accv = 0.f;
    for (int s = 0; s <= l; s++) accv += Gs[l][s] * Xs[s][p];
    y[((row0 + l) * NH + h) * HD + p] = accv;
  }
}

// ---------------- chunk states per (b,c,h) ----------------
__global__ __launch_bounds__(256) void ssd_states(const bf16* __restrict__ zx,
                                                  const float* __restrict__ Bn,
                                                  const float* __restrict__ dt,
                                                  const float* __restrict__ acum,
                                                  float* __restrict__ states) {
  __shared__ float Bs[64][129];
  __shared__ float Xs[64][64];
  __shared__ float dec[64];
  int bid = blockIdx.x;
  int h = bid % NH;
  int c = (bid / NH) % NC;
  int b = bid / (NH * NC);
  int tid = threadIdx.x;
  size_t row0 = (size_t)(b * S_ + c * CH);
  if (tid < CH) {
    float a63 = acum[(row0 + CH - 1) * NH + h];
    float as  = acum[(row0 + tid) * NH + h];
    dec[tid] = __expf(a63 - as);
  }
  for (int e = tid; e < CH * DS; e += 256) {
    int l = e >> 7, n = e & 127;
    Bs[l][n] = Bn[(row0 + l) * DS + n];
  }
  for (int e = tid; e < CH * HD; e += 256) {
    int l = e >> 6, p = e & 63;
    Xs[l][p] = (float)zx[(row0 + l) * DP + DI + h * HD + p] * dt[(row0 + l) * NH + h];
  }
  __syncthreads();
  for (int e = tid; e < HD * DS; e += 256) {
    int p = e >> 7, n = e & 127;
    float accv = 0.f;
#pragma unroll 4
    for (int s = 0; s < CH; s++) accv += dec[s] * Xs[s][p] * Bs[s][n];
    states[(size_t)bid * (HD * DS) + e] = accv;
  }
}

// ---------------- inter-chunk scan (in place) ----------------
__global__ __launch_bounds__(256) void ssd_scan(float* __restrict__ states,
                                                const float* __restrict__ T) {
  __shared__ float eT[NC];
  int part = blockIdx.x & 7;
  int bh = blockIdx.x >> 3;
  int b = bh / NH, h = bh % NH;
  if (threadIdx.x < NC) eT[threadIdx.x] = __expf(T[(size_t)(b * NH + h) * NC + threadIdx.x]);
  __syncthreads();
  const size_t cstride = (size_t)NH * HD * DS;
  size_t base = ((size_t)b * NC * NH + h) * (HD * DS);
#pragma unroll
  for (int j = 0; j < 4; j++) {
    int e = part * 1024 + threadIdx.x + j * 256;
    float carry = 0.f;
    size_t idx = base + e;
    for (int c = 0; c < NC; c++) {
      float sv = states[idx];
      states[idx] = carry;
      carry = sv + eT[c] * carry;
      idx += cstride;
    }
  }
}

// ---------------- Y_off + D skip + silu(z) gating per (b,c,h) ----------------
__global__ __launch_bounds__(256) void ssd_yoff(const bf16* __restrict__ zx,
                                                const float* __restrict__ Cn,
                                                const float* __restrict__ acum,
                                                const float* __restrict__ nstates,
                                                const float* __restrict__ Dp,
                                                const float* __restrict__ y,
                                                bf16* __restrict__ ybf) {
  __shared__ float Cs[64][64];
  __shared__ float Ns[64][65];
  __shared__ float ac[64];
  int bid = blockIdx.x;
  int h = bid % NH;
  int c = (bid / NH) % NC;
  int b = bid / (NH * NC);
  int tid = threadIdx.x;
  size_t row0 = (size_t)(b * S_ + c * CH);
  if (tid < CH) ac[tid] = acum[(row0 + tid) * NH + h];
  float acc[16] = {};
  for (int half = 0; half < 2; half++) {
    for (int e = tid; e < 64 * 64; e += 256) {
      int l = e >> 6, n = e & 63;
      Cs[l][n] = Cn[(row0 + l) * DS + half * 64 + n];
      Ns[l][n] = nstates[(size_t)bid * (HD * DS) + (size_t)l * DS + half * 64 + n];
    }
    __syncthreads();
#pragma unroll
    for (int j = 0; j < 16; j++) {
      int e = tid + j * 256;
      int l = e >> 6, p = e & 63;
      float d = acc[j];
      for (int n = 0; n < 64; n++) d += Cs[l][n] * Ns[p][n];
      acc[j] = d;
    }
    __syncthreads();
  }
#pragma unroll
  for (int j = 0; j < 16; j++) {
    int e = tid + j * 256;
    int l = e >> 6, p = e & 63;
    size_t row = row0 + l;
    size_t yi = (row * NH + h) * HD + p;
    float yv = y[yi] + acc[j] * __expf(ac[l]);
    float xs = (float)zx[row * DP + DI + h * HD + p];
    yv += xs * Dp[h];
    float z = (float)zx[row * DP + h * HD + p];
    yv *= z / (1.f + __expf(-z));
    ybf[yi] = (bf16)yv;
  }
}

// ---------------- q/k rmsnorm + rope + gain (f32 in place) ----------------
__global__ __launch_bounds__(64) void qk_prep(float* __restrict__ q,
                                              float* __restrict__ k,
                                              const float* __restrict__ q_gain) {
  int bid = blockIdx.x;
  int hh = bid % (HATT + KVH);
  size_t row = bid / (HATT + KVH);
  int s = (int)(row % S_);
  int d = threadIdx.x;
  bool isq = hh < HATT;
  float* vec = isq ? (q + row * (HATT * HD) + hh * HD)
                   : (k + row * (KVH * HD) + (hh - HATT) * HD);
  float v = vec[d];
  float ss = v * v;
#pragma unroll
  for (int off = 32; off > 0; off >>= 1) ss += __shfl_xor(ss, off, 64);
  v *= rsqrtf(ss / 64.f + 1.1920929e-7f);
  float res = v;
  if (d < RD) {
    int i = d & 7;
    float inv = __expf(-(float)i * (0.125f * 9.210340371976184f)); // 10000^(-i/8)
    float ang = (float)s * inv;
    float cs = cosf(ang), sn = sinf(ang);
    float other = __shfl_xor(v, 8, 64);
    res = (d < 8) ? (v * cs + other * sn) : (v * cs - other * sn);
  }
  if (isq) res *= q_gain[hh];
  vec[d] = res;
}

// ---------------- MFMA flash attention ----------------
// Computes S^T = K·Q^T (so per-q-row softmax reduces across quads in-wave),
// then Y^T = V^T·P^T. Per block: 64 q rows, loop over 64-row K/V tiles.
#define APAD 88   // padded LDS row (bf16 elems): 176 B = 16B-aligned, 2-way banks
__global__ __launch_bounds__(256) void attn_mfma(const float* __restrict__ q,
                                                 const float* __restrict__ k,
                                                 const float* __restrict__ v,
                                                 bf16* __restrict__ o) {
  __shared__ bf16 Qs[64 * APAD];
  __shared__ bf16 Ks[64 * APAD];
  __shared__ bf16 Vt[64 * APAD];
  __shared__ bf16 Pl[4 * 16 * APAD];
  int qt = (gridDim.x - 1) - blockIdx.x;   // big tiles first
  int h = blockIdx.y, b = blockIdx.z;
  int kvh = h >> 2;
  int tid = threadIdx.x, lane = tid & 63, w = tid >> 6;
  int fr = lane & 15, fq = lane >> 4;
  // stage Q tile (f32 -> bf16)
  for (int e = tid; e < 64 * 16; e += 256) {
    int r = e >> 4, c4 = (e & 15) << 2;
    const float4 qv = *(const float4*)(q + (size_t)(b * S_ + qt * 64 + r) * (HATT * HD) + h * HD + c4);
    Qs[r * APAD + c4 + 0] = (bf16)qv.x;
    Qs[r * APAD + c4 + 1] = (bf16)qv.y;
    Qs[r * APAD + c4 + 2] = (bf16)qv.z;
    Qs[r * APAD + c4 + 3] = (bf16)qv.w;
  }
  __syncthreads();
  bf16x8 bq0 = *(const bf16x8*)(Qs + (w * 16 + fr) * APAD + fq * 8);
  bf16x8 bq1 = *(const bf16x8*)(Qs + (w * 16 + fr) * APAD + 32 + fq * 8);
  int qpos = qt * 64 + w * 16 + fr;
  float m_run = -1e30f, lsum = 0.f;
  f32x4 yacc[4] = {};
  bf16* Plw = Pl + w * 16 * APAD;
  for (int kt = 0; kt <= qt; kt++) {
    __syncthreads();   // previous iteration's V/P reads done
    for (int e = tid; e < 64 * 16; e += 256) {
      int r = e >> 4, c4 = (e & 15) << 2;
      size_t base = (size_t)(b * S_ + kt * 64 + r) * (KVH * HD) + kvh * HD + c4;
      const float4 kv = *(const float4*)(k + base);
      const float4 vv = *(const float4*)(v + base);
      Ks[r * APAD + c4 + 0] = (bf16)kv.x;
      Ks[r * APAD + c4 + 1] = (bf16)kv.y;
      Ks[r * APAD + c4 + 2] = (bf16)kv.z;
      Ks[r * APAD + c4 + 3] = (bf16)kv.w;
      Vt[(c4 + 0) * APAD + r] = (bf16)vv.x;
      Vt[(c4 + 1) * APAD + r] = (bf16)vv.y;
      Vt[(c4 + 2) * APAD + r] = (bf16)vv.z;
      Vt[(c4 + 3) * APAD + r] = (bf16)vv.w;
    }
    __syncthreads();
    // S^T tiles: D[krow][qcol]
    f32x4 sacc[4] = {};
#pragma unroll
    for (int mi = 0; mi < 4; mi++) {
      bf16x8 ak0 = *(const bf16x8*)(Ks + (mi * 16 + fr) * APAD + fq * 8);
      bf16x8 ak1 = *(const bf16x8*)(Ks + (mi * 16 + fr) * APAD + 32 + fq * 8);
      sacc[mi] = __builtin_amdgcn_mfma_f32_16x16x32_bf16(ak0, bq0, sacc[mi], 0, 0, 0);
      sacc[mi] = __builtin_amdgcn_mfma_f32_16x16x32_bf16(ak1, bq1, sacc[mi], 0, 0, 0);
    }
    float lm = -1e30f;
    float sv[16];
#pragma unroll
    for (int mi = 0; mi < 4; mi++)
#pragma unroll
      for (int r = 0; r < 4; r++) {
        int kpos = kt * 64 + mi * 16 + fq * 4 + r;
        float s = sacc[mi][r] * 0.125f;
        if (kpos > qpos) s = -1e30f;
        sv[mi * 4 + r] = s;
        lm = fmaxf(lm, s);
      }
    lm = fmaxf(lm, __shfl_xor(lm, 16, 64));
    lm = fmaxf(lm, __shfl_xor(lm, 32, 64));
    float mnew = fmaxf(m_run, lm);
    float alpha = __expf(m_run - mnew);
    m_run = mnew;
    float ls = 0.f;
#pragma unroll
    for (int mi = 0; mi < 4; mi++) {
      bf16x4 pk;
#pragma unroll
      for (int r = 0; r < 4; r++) {
        float p = __expf(sv[mi * 4 + r] - mnew);
        ls += p;
        pk[r] = (bf16)p;
      }
      *(bf16x4*)(Plw + fr * APAD + mi * 16 + fq * 4) = pk;   // P^T stored as Pl[l][j]
    }
    ls += __shfl_xor(ls, 16, 64);
    ls += __shfl_xor(ls, 32, 64);
    lsum = lsum * alpha + ls;
#pragma unroll
    for (int pi = 0; pi < 4; pi++) yacc[pi] *= alpha;
    bf16x8 bp0 = *(const bf16x8*)(Plw + fr * APAD + fq * 8);        // wave-private, compiler waits
    bf16x8 bp1 = *(const bf16x8*)(Plw + fr * APAD + 32 + fq * 8);
#pragma unroll
    for (int pi = 0; pi < 4; pi++) {
      bf16x8 av0 = *(const bf16x8*)(Vt + (pi * 16 + fr) * APAD + fq * 8);
      bf16x8 av1 = *(const bf16x8*)(Vt + (pi * 16 + fr) * APAD + 32 + fq * 8);
      yacc[pi] = __builtin_amdgcn_mfma_f32_16x16x32_bf16(av0, bp0, yacc[pi], 0, 0, 0);
      yacc[pi] = __builtin_amdgcn_mfma_f32_16x16x32_bf16(av1, bp1, yacc[pi], 0, 0, 0);
    }
  }
  float inv = 1.f / lsum;
  int l = w * 16 + fr;
#pragma unroll
  for (int pi = 0; pi < 4; pi++)
#pragma unroll
    for (int r = 0; r < 4; r++) {
      int p = pi * 16 + fq * 4 + r;
      o[(size_t)(b * S_ + qt * 64 + l) * (HATT * HD) + h * HD + p] = (bf16)(yacc[pi][r] * inv);
    }
}

// ---------------- workspace layout (byte offsets) ----------------
constexpr size_t OFF_WIN  = 0;                       // bf16 4480x1024
constexpr size_t OFF_WOUT = 9175040;                 // bf16 1024x2048
constexpr size_t OFF_WQ   = 13369344;                // bf16 1024x1024
constexpr size_t OFF_WK   = 15466496;                // bf16 256x1024
constexpr size_t OFF_WV   = 15990784;                // bf16 256x1024
constexpr size_t OFF_WCP  = 16515072;                // bf16 1024x1024
constexpr size_t OFF_WFC  = 18612224;                // bf16 3072x1024
constexpr size_t OFF_WPR  = 24903680;                // bf16 1024x3072
constexpr size_t OFF_HBF  = 31195136;                // bf16 4096x1024
constexpr size_t OFF_ZX   = 39583744;                // bf16 4096x4384
constexpr size_t OFF_DT   = 75497472;                // f32 4096x32
constexpr size_t OFF_AC   = 76021760;                // f32 4096x32
constexpr size_t OFF_T    = 76546048;                // f32 2048
constexpr size_t OFF_BN   = 76554240;                // f32 4096x128
constexpr size_t OFF_CN   = 78651392;                // f32 4096x128
constexpr size_t OFF_CB   = 80748544;                // f32 64x4096
constexpr size_t OFF_STT  = 81797120;                // f32 2048x64x128
constexpr size_t OFF_YB   = 148905984;               // f32 4096x2048
constexpr size_t OFF_YBF  = 182460416;               // bf16 4096x2048  (end 199,237,632)
// aliases
constexpr size_t OFF_X1   = OFF_YB;                  // f32 4096x1024 (yb f32 dead)
constexpr size_t OFF_Q    = OFF_ZX;                  // f32 4096x1024 (zx dead)
constexpr size_t OFF_KB   = 56360960;                // f32 4096x256
constexpr size_t OFF_VB   = 60555264;                // f32 4096x256
constexpr size_t OFF_Y2   = 64749568;                // bf16 4096x1024
constexpr size_t OFF_X2   = OFF_STT;                 // f32 4096x1024 (states dead)
constexpr size_t OFF_MLP  = 98574336;                // bf16 4096x3072

extern "C" void kernel_launch(void* const* d_in, const int* in_sizes, int n_in,
                              void* d_out, int out_size, void* d_ws, size_t ws_size,
                              hipStream_t stream) {
  (void)in_sizes; (void)n_in; (void)out_size; (void)ws_size;
  const float* x        = (const float*)d_in[0];
  const float* mnorm_w  = (const float*)d_in[1];
  const float* in_w     = (const float*)d_in[2];
  const float* out_w    = (const float*)d_in[3];
  const float* Dp       = (const float*)d_in[4];
  const float* dt_bias  = (const float*)d_in[5];
  const float* A_log    = (const float*)d_in[6];
  const float* Bn_w     = (const float*)d_in[7];
  const float* Cn_w     = (const float*)d_in[8];
  const float* ln1_w    = (const float*)d_in[9];
  const float* ln1_b    = (const float*)d_in[10];
  const float* cq_w     = (const float*)d_in[11];
  const float* ck_w     = (const float*)d_in[12];
  const float* cv_w     = (const float*)d_in[13];
  const float* cproj_w  = (const float*)d_in[14];
  const float* q_gain   = (const float*)d_in[15];
  const float* ln2_w    = (const float*)d_in[16];
  const float* ln2_b    = (const float*)d_in[17];
  const float* fc_w     = (const float*)d_in[18];
  const float* proj_w   = (const float*)d_in[19];
  float* out = (float*)d_out;
  char* W8 = (char*)d_ws;

  bf16* w_in  = (bf16*)(W8 + OFF_WIN);
  bf16* w_out = (bf16*)(W8 + OFF_WOUT);
  bf16* w_q   = (bf16*)(W8 + OFF_WQ);
  bf16* w_k   = (bf16*)(W8 + OFF_WK);
  bf16* w_v   = (bf16*)(W8 + OFF_WV);
  bf16* w_cp  = (bf16*)(W8 + OFF_WCP);
  bf16* w_fc  = (bf16*)(W8 + OFF_WFC);
  bf16* w_pr  = (bf16*)(W8 + OFF_WPR);
  bf16* h_bf  = (bf16*)(W8 + OFF_HBF);
  bf16* zx    = (bf16*)(W8 + OFF_ZX);
  float* dt   = (float*)(W8 + OFF_DT);
  float* acum = (float*)(W8 + OFF_AC);
  float* Tb   = (float*)(W8 + OFF_T);
  float* Bn   = (float*)(W8 + OFF_BN);
  float* Cn   = (float*)(W8 + OFF_CN);
  float* CB   = (float*)(W8 + OFF_CB);
  float* st   = (float*)(W8 + OFF_STT);
  float* yb   = (float*)(W8 + OFF_YB);
  bf16* ybf   = (bf16*)(W8 + OFF_YBF);
  float* x1   = (float*)(W8 + OFF_X1);
  float* qf   = (float*)(W8 + OFF_Q);
  float* kf   = (float*)(W8 + OFF_KB);
  float* vf   = (float*)(W8 + OFF_VB);
  bf16* y2    = (bf16*)(W8 + OFF_Y2);
  float* x2   = (float*)(W8 + OFF_X2);
  bf16* mlp   = (bf16*)(W8 + OFF_MLP);

  // ---- weight casts (every call; ws is re-poisoned) ----
  castw<<<4480, 256, 0, stream>>>(in_w,    w_in,  4489216, 4587520);
  castw<<<2048, 256, 0, stream>>>(out_w,   w_out, 2097152, 2097152);
  castw<<<1024, 256, 0, stream>>>(cq_w,    w_q,   1048576, 1048576);
  castw<<< 256, 256, 0, stream>>>(ck_w,    w_k,    262144,  262144);
  castw<<< 256, 256, 0, stream>>>(cv_w,    w_v,    262144,  262144);
  castw<<<1024, 256, 0, stream>>>(cproj_w, w_cp,  1048576, 1048576);
  castw<<<3072, 256, 0, stream>>>(fc_w,    w_fc,  3145728, 3145728);
  castw<<<3072, 256, 0, stream>>>(proj_w,  w_pr,  3145728, 3145728);

  // ---- mamba block ----
  rmsnorm_k<<<ROWS, 256, 0, stream>>>(x, mnorm_w, h_bf, D_);
  gemm_mfma<0, bf16><<<dim3(35, 32), 256, 0, stream>>>(h_bf, w_in, nullptr, zx, ROWS, DP, D_);
  ssd_prep<<<B_ * NC * NH, 64, 0, stream>>>(zx, dt_bias, A_log, dt, acum, Tb);
  bc_norm<<<ROWS, 128, 0, stream>>>(zx, Bn_w, Cn_w, Bn, Cn);
  cb_dot<<<B_ * NC, 256, 0, stream>>>(Bn, Cn, CB);
  ssd_ydiag<<<B_ * NC * NH, 256, 0, stream>>>(zx, CB, dt, acum, yb);
  ssd_states<<<B_ * NC * NH, 256, 0, stream>>>(zx, Bn, dt, acum, st);
  ssd_scan<<<B_ * NH * 8, 256, 0, stream>>>(st, Tb);
  ssd_yoff<<<B_ * NC * NH, 256, 0, stream>>>(zx, Cn, acum, st, Dp, yb, ybf);
  gemm_mfma<0, float><<<dim3(8, 32), 256, 0, stream>>>(ybf, w_out, x, x1, ROWS, D_, DI);

  // ---- attention block ----
  layernorm_k<<<ROWS, 256, 0, stream>>>(x1, ln1_w, ln1_b, h_bf, D_);
  gemm_mfma<0, float><<<dim3(8, 32), 256, 0, stream>>>(h_bf, w_q, nullptr, qf, ROWS, D_, D_);
  gemm_mfma<0, float><<<dim3(2, 32), 256, 0, stream>>>(h_bf, w_k, nullptr, kf, ROWS, KVH * HD, D_);
  gemm_mfma<0, float><<<dim3(2, 32), 256, 0, stream>>>(h_bf, w_v, nullptr, vf, ROWS, KVH * HD, D_);
  qk_prep<<<ROWS * (HATT + KVH), 64, 0, stream>>>(qf, kf, q_gain);
  attn_mfma<<<dim3(S_ / 64, HATT, B_), 256, 0, stream>>>(qf, kf, vf, y2);
  gemm_mfma<0, float><<<dim3(8, 32), 256, 0, stream>>>(y2, w_cp, x1, x2, ROWS, D_, D_);

  // ---- MLP ----
  layernorm_k<<<ROWS, 256, 0, stream>>>(x2, ln2_w, ln2_b, h_bf, D_);
  gemm_mfma<1, bf16><<<dim3(24, 32), 256, 0, stream>>>(h_bf, w_fc, nullptr, mlp, ROWS, MLP, D_);
  gemm_mfma<0, float><<<dim3(8, 32), 256, 0, stream>>>(mlp, w_pr, x2, out, ROWS, D_, MLP);
}

// Round 3
// 723.916 us; speedup vs baseline: 6.1161x; 1.5333x over previous
//
#include <hip/hip_runtime.h>
#include <hip/hip_bf16.h>
#include <math.h>

// ---------------- problem constants ----------------
#define B_    2
#define S_    2048
#define D_    1024
#define DI    2048      // D_INNER
#define NH    32        // NHEADS (mamba)
#define HD    64        // HEADDIM
#define DS    128       // D_STATE
#define CH    64        // CHUNK
#define NC    32        // S_/CH
#define DP    4384      // D_PROJ
#define HATT  16        // attention heads
#define KVH   4         // kv heads
#define RD    16        // rope dims
#define MLP   3072
#define ROWS  (B_*S_)   // 4096

typedef __bf16 bf16;
typedef __bf16 bf16x8 __attribute__((ext_vector_type(8)));
typedef __bf16 bf16x4 __attribute__((ext_vector_type(4)));
typedef float  f32x4  __attribute__((ext_vector_type(4)));

__device__ __forceinline__ void async_copy16(const void* g, void* l) {
  __builtin_amdgcn_global_load_lds(
      (const __attribute__((address_space(1))) unsigned int*)g,
      (__attribute__((address_space(3))) unsigned int*)l, 16, 0, 0);
}

// ---------------- reductions ----------------
__device__ __forceinline__ float waveReduceSum(float v) {
#pragma unroll
  for (int off = 32; off > 0; off >>= 1) v += __shfl_down(v, off, 64);
  return v;
}

template<int NW>
__device__ __forceinline__ float blockReduceSum(float v, float* sh) {
  v = waveReduceSum(v);
  int lane = threadIdx.x & 63, wid = threadIdx.x >> 6;
  if (lane == 0) sh[wid] = v;
  __syncthreads();
  float s = 0.f;
#pragma unroll
  for (int i = 0; i < NW; i++) s += sh[i];
  __syncthreads();
  return s;
}

// ---------------- merged weight cast f32 -> bf16 ----------------
struct CastSeg { const float* src; bf16* dst; int nval; int ntot; int blk0; };
struct CastArgs { CastSeg seg[8]; };

__global__ __launch_bounds__(256) void castw_all(CastArgs a) {
  int blk = blockIdx.x;
  int si = 0;
#pragma unroll
  for (int i = 1; i < 8; i++) if (blk >= a.seg[i].blk0) si = i;
  CastSeg s = a.seg[si];
  int i = ((blk - s.blk0) * 256 + threadIdx.x) * 4;
  if (i >= s.ntot) return;
  float4 v = {0.f, 0.f, 0.f, 0.f};
  if (i < s.nval) v = *(const float4*)(s.src + i);
  bf16x4 o;
  o[0] = (bf16)v.x; o[1] = (bf16)v.y; o[2] = (bf16)v.z; o[3] = (bf16)v.w;
  *(bf16x4*)(s.dst + i) = o;
}

// ---------------- norm kernels (f32 in, bf16 out) ----------------
__global__ __launch_bounds__(256) void rmsnorm_k(const float* __restrict__ x,
                                                 const float* __restrict__ w,
                                                 bf16* __restrict__ y, int n) {
  __shared__ float sh[4];
  size_t row = blockIdx.x;
  const float* xr = x + row * n;
  bf16* yr = y + row * n;
  float ss = 0.f;
  for (int i = threadIdx.x; i < n; i += 256) { float v = xr[i]; ss += v * v; }
  ss = blockReduceSum<4>(ss, sh);
  float inv = rsqrtf(ss / n + 1e-5f);
  for (int i = threadIdx.x; i < n; i += 256) yr[i] = (bf16)(xr[i] * inv * w[i]);
}

__global__ __launch_bounds__(256) void layernorm_k(const float* __restrict__ x,
                                                   const float* __restrict__ w,
                                                   const float* __restrict__ b,
                                                   bf16* __restrict__ y, int n) {
  __shared__ float sh[4];
  size_t row = blockIdx.x;
  const float* xr = x + row * n;
  bf16* yr = y + row * n;
  float s = 0.f, s2 = 0.f;
  for (int i = threadIdx.x; i < n; i += 256) { float v = xr[i]; s += v; s2 += v * v; }
  s  = blockReduceSum<4>(s,  sh);
  s2 = blockReduceSum<4>(s2, sh);
  float mean = s / n;
  float var  = s2 / n - mean * mean;
  float inv  = rsqrtf(var + 1e-5f);
  for (int i = threadIdx.x; i < n; i += 256)
    yr[i] = (bf16)((xr[i] - mean) * inv * w[i] + b[i]);
}

// ---------------- generic bf16 MFMA GEMM: C = act(A @ W^T) (+R) ----------------
template<int ACT, typename OT>
__global__ __launch_bounds__(256) void gemm_mfma(const bf16* __restrict__ A,
                                                 const bf16* __restrict__ W,
                                                 const float* __restrict__ R,
                                                 OT* __restrict__ C,
                                                 int M, int N, int K) {
  __shared__ bf16 As[128 * 32];
  __shared__ bf16 Ws[128 * 32];
  int tid = threadIdx.x, lane = tid & 63, wave = tid >> 6;
  int bm = blockIdx.y * 128, bn = blockIdx.x * 128;
  const bf16* gA0 = A + (size_t)(bm + wave * 32 + (lane >> 2)) * K + (lane & 3) * 8;
  const bf16* gA1 = gA0 + (size_t)16 * K;
  const bf16* gW0 = W + (size_t)(bn + wave * 32 + (lane >> 2)) * K + (lane & 3) * 8;
  const bf16* gW1 = gW0 + (size_t)16 * K;
  bf16* lA0 = As + wave * 32 * 32;
  bf16* lA1 = lA0 + 16 * 32;
  bf16* lW0 = Ws + wave * 32 * 32;
  bf16* lW1 = lW0 + 16 * 32;
  int fr = lane & 15, fq = lane >> 4;
  int wm = wave >> 1, wn = wave & 1;
  const bf16* pA = As + (wm * 64 + fr) * 32 + fq * 8;
  const bf16* pW = Ws + (wn * 64 + fr) * 32 + fq * 8;
  f32x4 acc[4][4] = {};
  for (int k0 = 0; k0 < K; k0 += 32) {
    async_copy16(gA0, lA0);
    async_copy16(gA1, lA1);
    async_copy16(gW0, lW0);
    async_copy16(gW1, lW1);
    gA0 += 32; gA1 += 32; gW0 += 32; gW1 += 32;
    __syncthreads();
    bf16x8 af[4], bfr[4];
#pragma unroll
    for (int mi = 0; mi < 4; mi++) af[mi] = *(const bf16x8*)(pA + mi * 16 * 32);
#pragma unroll
    for (int ni = 0; ni < 4; ni++) bfr[ni] = *(const bf16x8*)(pW + ni * 16 * 32);
#pragma unroll
    for (int mi = 0; mi < 4; mi++)
#pragma unroll
      for (int ni = 0; ni < 4; ni++)
        acc[mi][ni] = __builtin_amdgcn_mfma_f32_16x16x32_bf16(af[mi], bfr[ni], acc[mi][ni], 0, 0, 0);
    __syncthreads();
  }
#pragma unroll
  for (int mi = 0; mi < 4; mi++) {
    int row = bm + wm * 64 + mi * 16 + fq * 4;
#pragma unroll
    for (int ni = 0; ni < 4; ni++) {
      int col = bn + wn * 64 + ni * 16 + fr;
      if (col < N) {
#pragma unroll
        for (int r = 0; r < 4; r++) {
          float v = acc[mi][ni][r];
          if (ACT == 1) v = v / (1.f + __expf(-v));
          if (R) v += R[(size_t)(row + r) * N + col];
          C[(size_t)(row + r) * N + col] = (OT)v;
        }
      }
    }
  }
}

// ---------------- in_proj GEMM: writes Zt/Xt transposed + compact bcdt ----------------
__global__ __launch_bounds__(256) void gemm_inproj(const bf16* __restrict__ A,
                                                   const bf16* __restrict__ W,
                                                   bf16* __restrict__ zt,
                                                   bf16* __restrict__ xt,
                                                   bf16* __restrict__ bcdt) {
  const int K = 1024;
  __shared__ bf16 As[128 * 32];
  __shared__ bf16 Ws[128 * 32];
  int tid = threadIdx.x, lane = tid & 63, wave = tid >> 6;
  int bm = blockIdx.y * 128, bn = blockIdx.x * 128;
  const bf16* gA0 = A + (size_t)(bm + wave * 32 + (lane >> 2)) * K + (lane & 3) * 8;
  const bf16* gA1 = gA0 + (size_t)16 * K;
  const bf16* gW0 = W + (size_t)(bn + wave * 32 + (lane >> 2)) * K + (lane & 3) * 8;
  const bf16* gW1 = gW0 + (size_t)16 * K;
  bf16* lA0 = As + wave * 32 * 32;
  bf16* lA1 = lA0 + 16 * 32;
  bf16* lW0 = Ws + wave * 32 * 32;
  bf16* lW1 = lW0 + 16 * 32;
  int fr = lane & 15, fq = lane >> 4;
  int wm = wave >> 1, wn = wave & 1;
  const bf16* pA = As + (wm * 64 + fr) * 32 + fq * 8;
  const bf16* pW = Ws + (wn * 64 + fr) * 32 + fq * 8;
  f32x4 acc[4][4] = {};
  for (int k0 = 0; k0 < K; k0 += 32) {
    async_copy16(gA0, lA0);
    async_copy16(gA1, lA1);
    async_copy16(gW0, lW0);
    async_copy16(gW1, lW1);
    gA0 += 32; gA1 += 32; gW0 += 32; gW1 += 32;
    __syncthreads();
    bf16x8 af[4], bfr[4];
#pragma unroll
    for (int mi = 0; mi < 4; mi++) af[mi] = *(const bf16x8*)(pA + mi * 16 * 32);
#pragma unroll
    for (int ni = 0; ni < 4; ni++) bfr[ni] = *(const bf16x8*)(pW + ni * 16 * 32);
#pragma unroll
    for (int mi = 0; mi < 4; mi++)
#pragma unroll
      for (int ni = 0; ni < 4; ni++)
        acc[mi][ni] = __builtin_amdgcn_mfma_f32_16x16x32_bf16(af[mi], bfr[ni], acc[mi][ni], 0, 0, 0);
    __syncthreads();
  }
#pragma unroll
  for (int mi = 0; mi < 4; mi++) {
    int row0m = bm + wm * 64 + mi * 16 + fq * 4;
    int b = row0m >> 11, sg = row0m & 2047;
#pragma unroll
    for (int ni = 0; ni < 4; ni++) {
      int col = bn + wn * 64 + ni * 16 + fr;
      bf16x4 o;
#pragma unroll
      for (int r = 0; r < 4; r++) o[r] = (bf16)acc[mi][ni][r];
      if (col < 2048) {
        *(bf16x4*)(zt + ((size_t)(b * NH + (col >> 6)) * HD + (col & 63)) * S_ + sg) = o;
      } else if (col < 4096) {
        int xc = col - 2048;
        *(bf16x4*)(xt + ((size_t)(b * NH + (xc >> 6)) * HD + (xc & 63)) * S_ + sg) = o;
      } else if (col < 4384) {
#pragma unroll
        for (int r = 0; r < 4; r++)
          bcdt[(size_t)(row0m + r) * 288 + (col - 4096)] = o[r];
      }
    }
  }
}

// ---------------- generic 64x64 tiled transpose (bf16), out row stride 2048 ----------------
__global__ __launch_bounds__(256) void t64(const bf16* __restrict__ in, bf16* __restrict__ out,
                                           int istr, size_t io, size_t oo, int n_nt) {
  __shared__ bf16 T[64 * 72];
  int bid = blockIdx.x;
  int st = bid & 31;
  int nt = (bid >> 5) % n_nt;
  int outer = bid / (32 * n_nt);
  const bf16* ip = in + outer * io + (size_t)st * 64 * istr + nt * 64;
  int tid = threadIdx.x;
#pragma unroll
  for (int i = 0; i < 2; i++) {
    int cid = tid + i * 256; int s = cid >> 3, pc = (cid & 7) * 8;
    *(bf16x8*)(T + s * 72 + pc) = *(const bf16x8*)(ip + (size_t)s * istr + pc);
  }
  __syncthreads();
  bf16* op = out + outer * oo + (size_t)nt * 64 * 2048 + st * 64;
#pragma unroll
  for (int i = 0; i < 2; i++) {
    int cid = tid + i * 256; int p = cid >> 3, sc = (cid & 7) * 8;
    bf16x8 o;
#pragma unroll
    for (int j = 0; j < 8; j++) o[j] = T[(sc + j) * 72 + p];
    *(bf16x8*)(op + (size_t)p * 2048 + sc) = o;
  }
}

// ---------------- SSD prep: dt softplus, per-chunk cumsum, decay factors ----------------
__global__ __launch_bounds__(64) void ssd_prep(const bf16* __restrict__ bcdt,
                                               const float* __restrict__ dt_bias,
                                               const float* __restrict__ A_log,
                                               float* __restrict__ dt_c,
                                               float* __restrict__ ddc,
                                               float* __restrict__ ac_c,
                                               float* __restrict__ T_out) {
  int bid = blockIdx.x;
  int c = bid % NC, hh = (bid / NC) % NH, b = bid / (NC * NH);
  int l = threadIdx.x;
  size_t row = (size_t)b * S_ + c * 64 + l;
  float raw = (float)bcdt[row * 288 + 256 + hh] + dt_bias[hh];
  float dtv = (raw > 20.f) ? raw : log1pf(__expf(raw));
  float a = -__expf(A_log[hh]) * dtv;
  float ps = a;
#pragma unroll
  for (int off = 1; off < 64; off <<= 1) {
    float t = __shfl_up(ps, off, 64);
    if (l >= off) ps += t;
  }
  float a63 = __shfl(ps, 63, 64);
  size_t o = ((size_t)b * NH + hh) * S_ + c * 64 + l;
  dt_c[o] = dtv;
  ac_c[o] = ps;
  ddc[o] = __expf(a63 - ps) * dtv;
  if (l == 63) T_out[(b * NH + hh) * NC + c] = ps;
}

// ---------------- B/C rmsnorm (bf16 out) ----------------
__global__ __launch_bounds__(128) void bc_norm(const bf16* __restrict__ bcdt,
                                               const float* __restrict__ Bw,
                                               const float* __restrict__ Cw,
                                               bf16* __restrict__ Bn,
                                               bf16* __restrict__ Cn) {
  __shared__ float shb[2], shc[2];
  size_t row = blockIdx.x;
  int i = threadIdx.x;
  float bv = (float)bcdt[row * 288 + i];
  float cv = (float)bcdt[row * 288 + 128 + i];
  float sb = waveReduceSum(bv * bv);
  float sc = waveReduceSum(cv * cv);
  int lane = threadIdx.x & 63, wid = threadIdx.x >> 6;
  if (lane == 0) { shb[wid] = sb; shc[wid] = sc; }
  __syncthreads();
  float tb = shb[0] + shb[1];
  float tc = shc[0] + shc[1];
  Bn[row * DS + i] = (bf16)(bv * rsqrtf(tb / DS + 1e-5f) * Bw[i]);
  Cn[row * DS + i] = (bf16)(cv * rsqrtf(tc / DS + 1e-5f) * Cw[i]);
}

// ---------------- chunk states via MFMA: states[p][n] = sum_s X[s][p]*dt*dec * B[s][n] ----------------
__global__ __launch_bounds__(256) void ssd_states(const bf16* __restrict__ Xt,
                                                  const bf16* __restrict__ Btr,
                                                  const float* __restrict__ ddc,
                                                  float* __restrict__ states) {
  __shared__ bf16 Xs[64 * 72];    // [p][s]
  __shared__ bf16 Bs[128 * 72];   // [n][s]
  int bid = blockIdx.x;           // (b*NC + c)*NH + h
  int h = bid % NH;
  int c = (bid / NH) % NC;
  int b = bid / (NH * NC);
  int tid = threadIdx.x, lane = tid & 63, w = tid >> 6;
  int fr = lane & 15, fq = lane >> 4;
  const size_t xbase = (size_t)(b * NH + h) * HD * S_ + c * 64;
  const size_t dbase = (size_t)(b * NH + h) * S_ + c * 64;
#pragma unroll
  for (int i = 0; i < 2; i++) {
    int cid = tid + i * 256; int p = cid >> 3, sc = (cid & 7) * 8;
    bf16x8 xv = *(const bf16x8*)(Xt + xbase + (size_t)p * S_ + sc);
    f32x4 d0 = *(const f32x4*)(ddc + dbase + sc);
    f32x4 d1 = *(const f32x4*)(ddc + dbase + sc + 4);
    bf16x8 o;
#pragma unroll
    for (int j = 0; j < 4; j++) { o[j] = (bf16)((float)xv[j] * d0[j]); o[4 + j] = (bf16)((float)xv[4 + j] * d1[j]); }
    *(bf16x8*)(Xs + p * 72 + sc) = o;
  }
  const size_t bbase = (size_t)b * 128 * S_ + c * 64;
#pragma unroll
  for (int i = 0; i < 4; i++) {
    int cid = tid + i * 256; int n = cid >> 3, sc = (cid & 7) * 8;
    *(bf16x8*)(Bs + n * 72 + sc) = *(const bf16x8*)(Btr + bbase + (size_t)n * S_ + sc);
  }
  __syncthreads();
  f32x4 acc[4][2] = {};
#pragma unroll
  for (int ks = 0; ks < 2; ks++) {
    bf16x8 a[4], bb[2];
#pragma unroll
    for (int pt = 0; pt < 4; pt++) a[pt] = *(const bf16x8*)(Xs + (pt * 16 + fr) * 72 + ks * 32 + fq * 8);
#pragma unroll
    for (int n2 = 0; n2 < 2; n2++) bb[n2] = *(const bf16x8*)(Bs + ((2 * w + n2) * 16 + fr) * 72 + ks * 32 + fq * 8);
#pragma unroll
    for (int pt = 0; pt < 4; pt++)
#pragma unroll
      for (int n2 = 0; n2 < 2; n2++)
        acc[pt][n2] = __builtin_amdgcn_mfma_f32_16x16x32_bf16(a[pt], bb[n2], acc[pt][n2], 0, 0, 0);
  }
  float* outp = states + (size_t)bid * 8192;
#pragma unroll
  for (int pt = 0; pt < 4; pt++)
#pragma unroll
    for (int n2 = 0; n2 < 2; n2++) {
      int n = (2 * w + n2) * 16 + fr;
#pragma unroll
      for (int r = 0; r < 4; r++)
        outp[(size_t)(pt * 16 + fq * 4 + r) * 128 + n] = acc[pt][n2][r];
    }
}

// ---------------- inter-chunk scan (in place) ----------------
__global__ __launch_bounds__(256) void ssd_scan(float* __restrict__ states,
                                                const float* __restrict__ T) {
  __shared__ float eT[NC];
  int part = blockIdx.x & 7;
  int bh = blockIdx.x >> 3;
  int b = bh / NH, h = bh % NH;
  if (threadIdx.x < NC) eT[threadIdx.x] = __expf(T[(size_t)(b * NH + h) * NC + threadIdx.x]);
  __syncthreads();
  const size_t cstride = (size_t)NH * HD * DS;
  size_t base = ((size_t)b * NC * NH + h) * (HD * DS);
#pragma unroll
  for (int j = 0; j < 4; j++) {
    int e = part * 1024 + threadIdx.x + j * 256;
    float carry = 0.f;
    size_t idx = base + e;
    for (int c = 0; c < NC; c++) {
      float sv = states[idx];
      states[idx] = carry;
      carry = sv + eT[c] * carry;
      idx += cstride;
    }
  }
}

// ---------------- fused SSD output: Ydiag + Yoff + D-skip + gate (all MFMA) ----------------
__global__ __launch_bounds__(256) void ssd_out(const bf16* __restrict__ Cn,
                                               const bf16* __restrict__ Bn,
                                               const bf16* __restrict__ Xt,
                                               const bf16* __restrict__ Zt,
                                               const float* __restrict__ dt_c,
                                               const float* __restrict__ ac_c,
                                               const float* __restrict__ states,
                                               const float* __restrict__ Dp,
                                               bf16* __restrict__ ybf) {
  __shared__ bf16 Cs[64 * 136];   // [l][n], pre-scaled by exp(ac[l])
  __shared__ bf16 BNs[64 * 136];  // [s][n] for CB phase; reused as Ns[p][n]
  __shared__ bf16 Xs[64 * 72];    // [p][s], dt-scaled
  __shared__ bf16 G[64 * 72];     // [l][s]
  __shared__ float acs[64];
  int bid = blockIdx.x;           // (b*NC + c)*NH + h
  int h = bid % NH;
  int c = (bid / NH) % NC;
  int b = bid / (NH * NC);
  int tid = threadIdx.x, lane = tid & 63, w = tid >> 6;
  int fr = lane & 15, fq = lane >> 4;
  size_t row0 = (size_t)b * S_ + c * 64;
  const size_t abase = (size_t)(b * NH + h) * S_ + c * 64;
  if (tid < 64) acs[tid] = ac_c[abase + tid];
  // stage Cs (scaled), Bs
#pragma unroll
  for (int i = 0; i < 4; i++) {
    int cid = tid + i * 256; int l = cid >> 4, nc = (cid & 15) * 8;
    float e = __expf(ac_c[abase + l]);
    bf16x8 cv = *(const bf16x8*)(Cn + (row0 + l) * DS + nc);
    bf16x8 o;
#pragma unroll
    for (int j = 0; j < 8; j++) o[j] = (bf16)((float)cv[j] * e);
    *(bf16x8*)(Cs + l * 136 + nc) = o;
    *(bf16x8*)(BNs + l * 136 + nc) = *(const bf16x8*)(Bn + (row0 + l) * DS + nc);
  }
  // stage Xs (dt-scaled)
  const size_t xbase = (size_t)(b * NH + h) * HD * S_ + c * 64;
#pragma unroll
  for (int i = 0; i < 2; i++) {
    int cid = tid + i * 256; int p = cid >> 3, sc = (cid & 7) * 8;
    bf16x8 xv = *(const bf16x8*)(Xt + xbase + (size_t)p * S_ + sc);
    f32x4 d0 = *(const f32x4*)(dt_c + abase + sc);
    f32x4 d1 = *(const f32x4*)(dt_c + abase + sc + 4);
    bf16x8 o;
#pragma unroll
    for (int j = 0; j < 4; j++) { o[j] = (bf16)((float)xv[j] * d0[j]); o[4 + j] = (bf16)((float)xv[4 + j] * d1[j]); }
    *(bf16x8*)(Xs + p * 72 + sc) = o;
  }
  __syncthreads();
  // phase 1: CB' = C' * B^T  (wave w owns l-tile w)
  bf16x8 ca[4];
#pragma unroll
  for (int ks = 0; ks < 4; ks++) ca[ks] = *(const bf16x8*)(Cs + (w * 16 + fr) * 136 + ks * 32 + fq * 8);
  f32x4 cb[4] = {};
  for (int st = 0; st <= w; st++)
#pragma unroll
    for (int ks = 0; ks < 4; ks++)
      cb[st] = __builtin_amdgcn_mfma_f32_16x16x32_bf16(ca[ks],
                 *(const bf16x8*)(BNs + (st * 16 + fr) * 136 + ks * 32 + fq * 8), cb[st], 0, 0, 0);
  // G = CB' * exp(-ac[s]) masked (l >= s)
#pragma unroll
  for (int st = 0; st < 4; st++) {
    float es = (st <= w) ? __expf(-acs[st * 16 + fr]) : 0.f;
#pragma unroll
    for (int r = 0; r < 4; r++) {
      int lloc = fq * 4 + r;
      float g = 0.f;
      if (st < w) g = cb[st][r] * es;
      else if (st == w) g = (lloc >= fr) ? cb[st][r] * es : 0.f;
      G[(w * 16 + lloc) * 72 + st * 16 + fr] = (bf16)g;
    }
  }
  // phase 2: Ydiag = G * X
  f32x4 acc[4] = {};
  {
    bf16x8 ga0 = *(const bf16x8*)(G + (w * 16 + fr) * 72 + fq * 8);
    bf16x8 ga1 = *(const bf16x8*)(G + (w * 16 + fr) * 72 + 32 + fq * 8);
#pragma unroll
    for (int pt = 0; pt < 4; pt++) {
      acc[pt] = __builtin_amdgcn_mfma_f32_16x16x32_bf16(ga0,
                  *(const bf16x8*)(Xs + (pt * 16 + fr) * 72 + fq * 8), acc[pt], 0, 0, 0);
      acc[pt] = __builtin_amdgcn_mfma_f32_16x16x32_bf16(ga1,
                  *(const bf16x8*)(Xs + (pt * 16 + fr) * 72 + 32 + fq * 8), acc[pt], 0, 0, 0);
    }
  }
  __syncthreads();
  // stage Ns (post-scan states for this chunk) over BNs
  const float* stp = states + (size_t)bid * 8192;
#pragma unroll
  for (int i = 0; i < 4; i++) {
    int cid = tid + i * 256; int p = cid >> 4, nc = (cid & 15) * 8;
    f32x4 s0 = *(const f32x4*)(stp + (size_t)p * 128 + nc);
    f32x4 s1 = *(const f32x4*)(stp + (size_t)p * 128 + nc + 4);
    bf16x8 o;
#pragma unroll
    for (int j = 0; j < 4; j++) { o[j] = (bf16)s0[j]; o[4 + j] = (bf16)s1[j]; }
    *(bf16x8*)(BNs + p * 136 + nc) = o;
  }
  __syncthreads();
  // phase 3: Yoff = C' * N^T, accumulate
#pragma unroll
  for (int pt = 0; pt < 4; pt++)
#pragma unroll
    for (int ks = 0; ks < 4; ks++)
      acc[pt] = __builtin_amdgcn_mfma_f32_16x16x32_bf16(ca[ks],
                  *(const bf16x8*)(BNs + (pt * 16 + fr) * 136 + ks * 32 + fq * 8), acc[pt], 0, 0, 0);
  // epilogue: D-skip + silu(z) gate
  float dph = Dp[h];
#pragma unroll
  for (int pt = 0; pt < 4; pt++) {
    int p = pt * 16 + fr;
    size_t tb = (xbase + (size_t)p * S_) + w * 16 + fq * 4;
    bf16x4 xs4 = *(const bf16x4*)(Xt + tb);
    bf16x4 z4  = *(const bf16x4*)(Zt + tb);
#pragma unroll
    for (int r = 0; r < 4; r++) {
      int l = w * 16 + fq * 4 + r;
      float yv = acc[pt][r] + (float)xs4[r] * dph;
      float z = (float)z4[r];
      yv *= z / (1.f + __expf(-z));
      ybf[((row0 + l) * NH + h) * HD + p] = (bf16)yv;
    }
  }
}

// ---------------- q/k rmsnorm + rope + gain (bf16 in place) ----------------
__global__ __launch_bounds__(64) void qk_prep(bf16* __restrict__ q,
                                              bf16* __restrict__ k,
                                              const float* __restrict__ q_gain) {
  int bid = blockIdx.x;
  int hh = bid % (HATT + KVH);
  size_t row = bid / (HATT + KVH);
  int s = (int)(row % S_);
  int d = threadIdx.x;
  bool isq = hh < HATT;
  bf16* vec = isq ? (q + row * (HATT * HD) + hh * HD)
                  : (k + row * (KVH * HD) + (hh - HATT) * HD);
  float v = (float)vec[d];
  float ss = v * v;
#pragma unroll
  for (int off = 32; off > 0; off >>= 1) ss += __shfl_xor(ss, off, 64);
  v *= rsqrtf(ss / 64.f + 1.1920929e-7f);
  float res = v;
  if (d < RD) {
    int i = d & 7;
    float inv = __expf(-(float)i * (0.125f * 9.210340371976184f));
    float ang = (float)s * inv;
    float cs = cosf(ang), sn = sinf(ang);
    float other = __shfl_xor(v, 8, 64);
    res = (d < 8) ? (v * cs + other * sn) : (v * cs - other * sn);
  }
  if (isq) res *= q_gain[hh];
  vec[d] = (bf16)res;
}

// ---------------- MFMA flash attention (bf16 in, V pre-transposed) ----------------
__global__ __launch_bounds__(256) void attn_mfma(const bf16* __restrict__ q,
                                                 const bf16* __restrict__ k,
                                                 const bf16* __restrict__ vtr,
                                                 bf16* __restrict__ o) {
  __shared__ bf16 Qs[64 * 72];
  __shared__ bf16 Ks[64 * 72];
  __shared__ bf16 Vt[64 * 72];
  __shared__ bf16 Pl[4 * 16 * 72];
  int qt = (gridDim.x - 1) - blockIdx.x;
  int h = blockIdx.y, b = blockIdx.z;
  int kvh = h >> 2;
  int tid = threadIdx.x, lane = tid & 63, w = tid >> 6;
  int fr = lane & 15, fq = lane >> 4;
#pragma unroll
  for (int i = 0; i < 2; i++) {
    int cid = tid + i * 256; int r = cid >> 3, c8 = (cid & 7) * 8;
    *(bf16x8*)(Qs + r * 72 + c8) =
        *(const bf16x8*)(q + (size_t)(b * S_ + qt * 64 + r) * (HATT * HD) + h * HD + c8);
  }
  __syncthreads();
  bf16x8 bq0 = *(const bf16x8*)(Qs + (w * 16 + fr) * 72 + fq * 8);
  bf16x8 bq1 = *(const bf16x8*)(Qs + (w * 16 + fr) * 72 + 32 + fq * 8);
  int qpos = qt * 64 + w * 16 + fr;
  float m_run = -1e30f, lsum = 0.f;
  f32x4 yacc[4] = {};
  bf16* Plw = Pl + w * 16 * 72;
  for (int kt = 0; kt <= qt; kt++) {
    __syncthreads();
#pragma unroll
    for (int i = 0; i < 2; i++) {
      int cid = tid + i * 256; int r = cid >> 3, c8 = (cid & 7) * 8;
      *(bf16x8*)(Ks + r * 72 + c8) =
          *(const bf16x8*)(k + (size_t)(b * S_ + kt * 64 + r) * (KVH * HD) + kvh * HD + c8);
      *(bf16x8*)(Vt + r * 72 + c8) =
          *(const bf16x8*)(vtr + ((size_t)(b * KVH + kvh) * HD + r) * S_ + (size_t)kt * 64 + c8);
    }
    __syncthreads();
    f32x4 sacc[4] = {};
#pragma unroll
    for (int mi = 0; mi < 4; mi++) {
      bf16x8 ak0 = *(const bf16x8*)(Ks + (mi * 16 + fr) * 72 + fq * 8);
      bf16x8 ak1 = *(const bf16x8*)(Ks + (mi * 16 + fr) * 72 + 32 + fq * 8);
      sacc[mi] = __builtin_amdgcn_mfma_f32_16x16x32_bf16(ak0, bq0, sacc[mi], 0, 0, 0);
      sacc[mi] = __builtin_amdgcn_mfma_f32_16x16x32_bf16(ak1, bq1, sacc[mi], 0, 0, 0);
    }
    float lm = -1e30f;
    float sv[16];
#pragma unroll
    for (int mi = 0; mi < 4; mi++)
#pragma unroll
      for (int r = 0; r < 4; r++) {
        int kpos = kt * 64 + mi * 16 + fq * 4 + r;
        float s = sacc[mi][r] * 0.125f;
        if (kpos > qpos) s = -1e30f;
        sv[mi * 4 + r] = s;
        lm = fmaxf(lm, s);
      }
    lm = fmaxf(lm, __shfl_xor(lm, 16, 64));
    lm = fmaxf(lm, __shfl_xor(lm, 32, 64));
    float mnew = fmaxf(m_run, lm);
    float alpha = __expf(m_run - mnew);
    m_run = mnew;
    float ls = 0.f;
#pragma unroll
    for (int mi = 0; mi < 4; mi++) {
      bf16x4 pk;
#pragma unroll
      for (int r = 0; r < 4; r++) {
        float p = __expf(sv[mi * 4 + r] - mnew);
        ls += p;
        pk[r] = (bf16)p;
      }
      *(bf16x4*)(Plw + fr * 72 + mi * 16 + fq * 4) = pk;
    }
    ls += __shfl_xor(ls, 16, 64);
    ls += __shfl_xor(ls, 32, 64);
    lsum = lsum * alpha + ls;
#pragma unroll
    for (int pi = 0; pi < 4; pi++) yacc[pi] *= alpha;
    bf16x8 bp0 = *(const bf16x8*)(Plw + fr * 72 + fq * 8);
    bf16x8 bp1 = *(const bf16x8*)(Plw + fr * 72 + 32 + fq * 8);
#pragma unroll
    for (int pi = 0; pi < 4; pi++) {
      bf16x8 av0 = *(const bf16x8*)(Vt + (pi * 16 + fr) * 72 + fq * 8);
      bf16x8 av1 = *(const bf16x8*)(Vt + (pi * 16 + fr) * 72 + 32 + fq * 8);
      yacc[pi] = __builtin_amdgcn_mfma_f32_16x16x32_bf16(av0, bp0, yacc[pi], 0, 0, 0);
      yacc[pi] = __builtin_amdgcn_mfma_f32_16x16x32_bf16(av1, bp1, yacc[pi], 0, 0, 0);
    }
  }
  float inv = 1.f / lsum;
  int l = w * 16 + fr;
#pragma unroll
  for (int pi = 0; pi < 4; pi++)
#pragma unroll
    for (int r = 0; r < 4; r++) {
      int p = pi * 16 + fq * 4 + r;
      o[(size_t)(b * S_ + qt * 64 + l) * (HATT * HD) + h * HD + p] = (bf16)(yacc[pi][r] * inv);
    }
}

// ---------------- workspace layout (byte offsets) ----------------
constexpr size_t OFF_WIN  = 0;                   // bf16 4480x1024
constexpr size_t OFF_WOUT = 9175040;             // bf16 1024x2048
constexpr size_t OFF_WQ   = 13369344;            // bf16 1024x1024
constexpr size_t OFF_WK   = 15466496;            // bf16 256x1024
constexpr size_t OFF_WV   = 15990784;            // bf16 256x1024
constexpr size_t OFF_WCP  = 16515072;            // bf16 1024x1024
constexpr size_t OFF_WFC  = 18612224;            // bf16 3072x1024
constexpr size_t OFF_WPR  = 24903680;            // bf16 1024x3072
constexpr size_t OFF_HBF  = 31195136;            // bf16 4096x1024
constexpr size_t OFF_BCDT = 39583744;            // bf16 4096x288
constexpr size_t OFF_XT   = 41943040;            // bf16 [b][h][p][sg]
constexpr size_t OFF_ZT   = 58720256;            // bf16 [b][h][p][sg]
constexpr size_t OFF_DTC  = 75497472;            // f32 [b][h][sg]
constexpr size_t OFF_DDC  = 76546048;            // f32
constexpr size_t OFF_ACC  = 77594624;            // f32
constexpr size_t OFF_T    = 78643200;            // f32 2048
constexpr size_t OFF_BN   = 78651392;            // bf16 4096x128
constexpr size_t OFF_CN   = 79699968;            // bf16 4096x128
constexpr size_t OFF_BTR  = 80748544;            // bf16 [b][n][sg]
constexpr size_t OFF_ST   = 81797120;            // f32 2048x64x128
constexpr size_t OFF_YBF  = 148905984;           // bf16 4096x2048
constexpr size_t OFF_X1   = 165683200;           // f32 4096x1024 (end 182,460,416)
// aliases inside the states region (dead after ssd_out)
constexpr size_t OFF_QB   = OFF_ST + 0;          // bf16 4096x1024
constexpr size_t OFF_KB   = OFF_ST + 8388608;    // bf16 4096x256
constexpr size_t OFF_VB   = OFF_ST + 10485760;   // bf16 4096x256
constexpr size_t OFF_VTR  = OFF_ST + 12582912;   // bf16 [b][kvh][p][sg]
constexpr size_t OFF_Y2   = OFF_ST + 14680064;   // bf16 4096x1024
constexpr size_t OFF_X2   = OFF_ST + 23068672;   // f32 4096x1024
constexpr size_t OFF_MLPB = OFF_ST + 39845888;   // bf16 4096x3072

extern "C" void kernel_launch(void* const* d_in, const int* in_sizes, int n_in,
                              void* d_out, int out_size, void* d_ws, size_t ws_size,
                              hipStream_t stream) {
  (void)in_sizes; (void)n_in; (void)out_size; (void)ws_size;
  const float* x        = (const float*)d_in[0];
  const float* mnorm_w  = (const float*)d_in[1];
  const float* in_w     = (const float*)d_in[2];
  const float* out_w    = (const float*)d_in[3];
  const float* Dp       = (const float*)d_in[4];
  const float* dt_bias  = (const float*)d_in[5];
  const float* A_log    = (const float*)d_in[6];
  const float* Bn_w     = (const float*)d_in[7];
  const float* Cn_w     = (const float*)d_in[8];
  const float* ln1_w    = (const float*)d_in[9];
  const float* ln1_b    = (const float*)d_in[10];
  const float* cq_w     = (const float*)d_in[11];
  const float* ck_w     = (const float*)d_in[12];
  const float* cv_w     = (const float*)d_in[13];
  const float* cproj_w  = (const float*)d_in[14];
  const float* q_gain   = (const float*)d_in[15];
  const float* ln2_w    = (const float*)d_in[16];
  const float* ln2_b    = (const float*)d_in[17];
  const float* fc_w     = (const float*)d_in[18];
  const float* proj_w   = (const float*)d_in[19];
  float* out = (float*)d_out;
  char* W8 = (char*)d_ws;

  bf16* w_in  = (bf16*)(W8 + OFF_WIN);
  bf16* w_out = (bf16*)(W8 + OFF_WOUT);
  bf16* w_q   = (bf16*)(W8 + OFF_WQ);
  bf16* w_k   = (bf16*)(W8 + OFF_WK);
  bf16* w_v   = (bf16*)(W8 + OFF_WV);
  bf16* w_cp  = (bf16*)(W8 + OFF_WCP);
  bf16* w_fc  = (bf16*)(W8 + OFF_WFC);
  bf16* w_pr  = (bf16*)(W8 + OFF_WPR);
  bf16* h_bf  = (bf16*)(W8 + OFF_HBF);
  bf16* bcdt  = (bf16*)(W8 + OFF_BCDT);
  bf16* Xt    = (bf16*)(W8 + OFF_XT);
  bf16* Zt    = (bf16*)(W8 + OFF_ZT);
  float* dt_c = (float*)(W8 + OFF_DTC);
  float* ddc  = (float*)(W8 + OFF_DDC);
  float* ac_c = (float*)(W8 + OFF_ACC);
  float* Tb   = (float*)(W8 + OFF_T);
  bf16* Bn    = (bf16*)(W8 + OFF_BN);
  bf16* Cn    = (bf16*)(W8 + OFF_CN);
  bf16* Btr   = (bf16*)(W8 + OFF_BTR);
  float* st   = (float*)(W8 + OFF_ST);
  bf16* ybf   = (bf16*)(W8 + OFF_YBF);
  float* x1   = (float*)(W8 + OFF_X1);
  bf16* qbf   = (bf16*)(W8 + OFF_QB);
  bf16* kbf   = (bf16*)(W8 + OFF_KB);
  bf16* vbf   = (bf16*)(W8 + OFF_VB);
  bf16* vtr   = (bf16*)(W8 + OFF_VTR);
  bf16* y2    = (bf16*)(W8 + OFF_Y2);
  float* x2   = (float*)(W8 + OFF_X2);
  bf16* mlp   = (bf16*)(W8 + OFF_MLPB);

  // ---- weight casts (single launch) ----
  CastArgs ca;
  ca.seg[0] = { in_w,    w_in, 4489216, 4587520, 0     };
  ca.seg[1] = { out_w,   w_out, 2097152, 2097152, 4480 };
  ca.seg[2] = { cq_w,    w_q,  1048576, 1048576, 6528  };
  ca.seg[3] = { ck_w,    w_k,   262144,  262144, 7552  };
  ca.seg[4] = { cv_w,    w_v,   262144,  262144, 7808  };
  ca.seg[5] = { cproj_w, w_cp, 1048576, 1048576, 8064  };
  ca.seg[6] = { fc_w,    w_fc, 3145728, 3145728, 9088  };
  ca.seg[7] = { proj_w,  w_pr, 3145728, 3145728, 12160 };
  castw_all<<<15232, 256, 0, stream>>>(ca);

  // ---- mamba block ----
  rmsnorm_k<<<ROWS, 256, 0, stream>>>(x, mnorm_w, h_bf, D_);
  gemm_inproj<<<dim3(35, 32), 256, 0, stream>>>(h_bf, w_in, Zt, Xt, bcdt);
  ssd_prep<<<B_ * NH * NC, 64, 0, stream>>>(bcdt, dt_bias, A_log, dt_c, ddc, ac_c, Tb);
  bc_norm<<<ROWS, 128, 0, stream>>>(bcdt, Bn_w, Cn_w, Bn, Cn);
  t64<<<2 * 2 * 32, 256, 0, stream>>>(Bn, Btr, 128, (size_t)2048 * 128, (size_t)128 * 2048, 2);
  ssd_states<<<B_ * NC * NH, 256, 0, stream>>>(Xt, Btr, ddc, st);
  ssd_scan<<<B_ * NH * 8, 256, 0, stream>>>(st, Tb);
  ssd_out<<<B_ * NC * NH, 256, 0, stream>>>(Cn, Bn, Xt, Zt, dt_c, ac_c, st, Dp, ybf);
  gemm_mfma<0, float><<<dim3(8, 32), 256, 0, stream>>>(ybf, w_out, x, x1, ROWS, D_, DI);

  // ---- attention block ----
  layernorm_k<<<ROWS, 256, 0, stream>>>(x1, ln1_w, ln1_b, h_bf, D_);
  gemm_mfma<0, bf16><<<dim3(8, 32), 256, 0, stream>>>(h_bf, w_q, nullptr, qbf, ROWS, D_, D_);
  gemm_mfma<0, bf16><<<dim3(2, 32), 256, 0, stream>>>(h_bf, w_k, nullptr, kbf, ROWS, KVH * HD, D_);
  gemm_mfma<0, bf16><<<dim3(2, 32), 256, 0, stream>>>(h_bf, w_v, nullptr, vbf, ROWS, KVH * HD, D_);
  t64<<<2 * 4 * 32, 256, 0, stream>>>(vbf, vtr, 256, (size_t)2048 * 256, (size_t)256 * 2048, 4);
  qk_prep<<<ROWS * (HATT + KVH), 64, 0, stream>>>(qbf, kbf, q_gain);
  attn_mfma<<<dim3(S_ / 64, HATT, B_), 256, 0, stream>>>(qbf, kbf, vtr, y2);
  gemm_mfma<0, float><<<dim3(8, 32), 256, 0, stream>>>(y2, w_cp, x1, x2, ROWS, D_, D_);

  // ---- MLP ----
  layernorm_k<<<ROWS, 256, 0, stream>>>(x2, ln2_w, ln2_b, h_bf, D_);
  gemm_mfma<1, bf16><<<dim3(24, 32), 256, 0, stream>>>(h_bf, w_fc, nullptr, mlp, ROWS, MLP, D_);
  gemm_mfma<0, float><<<dim3(8, 32), 256, 0, stream>>>(mlp, w_pr, x2, out, ROWS, D_, MLP);
}

// Round 4
// 605.814 us; speedup vs baseline: 7.3084x; 1.1949x over previous
//
#include <hip/hip_runtime.h>
#include <hip/hip_bf16.h>
#include <math.h>

// ---------------- problem constants ----------------
#define B_    2
#define S_    2048
#define D_    1024
#define DI    2048      // D_INNER
#define NH    32        // NHEADS (mamba)
#define HD    64        // HEADDIM
#define DS    128       // D_STATE
#define CH    64        // CHUNK
#define NC    32        // S_/CH
#define DP    4384      // D_PROJ
#define HATT  16        // attention heads
#define KVH   4         // kv heads
#define RD    16        // rope dims
#define MLP   3072
#define ROWS  (B_*S_)   // 4096

typedef __bf16 bf16;
typedef __bf16 bf16x8 __attribute__((ext_vector_type(8)));
typedef __bf16 bf16x4 __attribute__((ext_vector_type(4)));
typedef float  f32x4  __attribute__((ext_vector_type(4)));

__device__ __forceinline__ void async_copy16(const void* g, void* l) {
  __builtin_amdgcn_global_load_lds(
      (const __attribute__((address_space(1))) unsigned int*)g,
      (__attribute__((address_space(3))) unsigned int*)l, 16, 0, 0);
}

// ---------------- reductions ----------------
__device__ __forceinline__ float waveReduceSum(float v) {
#pragma unroll
  for (int off = 32; off > 0; off >>= 1) v += __shfl_down(v, off, 64);
  return v;
}

template<int NW>
__device__ __forceinline__ float blockReduceSum(float v, float* sh) {
  v = waveReduceSum(v);
  int lane = threadIdx.x & 63, wid = threadIdx.x >> 6;
  if (lane == 0) sh[wid] = v;
  __syncthreads();
  float s = 0.f;
#pragma unroll
  for (int i = 0; i < NW; i++) s += sh[i];
  __syncthreads();
  return s;
}

// ---------------- merged weight cast f32 -> bf16 ----------------
struct CastSeg { const float* src; bf16* dst; int nval; int ntot; int blk0; };
struct CastArgs { CastSeg seg[8]; };

__global__ __launch_bounds__(256) void castw_all(CastArgs a) {
  int blk = blockIdx.x;
  int si = 0;
#pragma unroll
  for (int i = 1; i < 8; i++) if (blk >= a.seg[i].blk0) si = i;
  CastSeg s = a.seg[si];
  int i = ((blk - s.blk0) * 256 + threadIdx.x) * 4;
  if (i >= s.ntot) return;
  float4 v = {0.f, 0.f, 0.f, 0.f};
  if (i < s.nval) v = *(const float4*)(s.src + i);
  bf16x4 o;
  o[0] = (bf16)v.x; o[1] = (bf16)v.y; o[2] = (bf16)v.z; o[3] = (bf16)v.w;
  *(bf16x4*)(s.dst + i) = o;
}

// ---------------- rmsnorm (f32 in, bf16 out) ----------------
__global__ __launch_bounds__(256) void rmsnorm_k(const float* __restrict__ x,
                                                 const float* __restrict__ w,
                                                 bf16* __restrict__ y, int n) {
  __shared__ float sh[4];
  size_t row = blockIdx.x;
  const float* xr = x + row * n;
  bf16* yr = y + row * n;
  float ss = 0.f;
  for (int i = threadIdx.x; i < n; i += 256) { float v = xr[i]; ss += v * v; }
  ss = blockReduceSum<4>(ss, sh);
  float inv = rsqrtf(ss / n + 1e-5f);
  for (int i = threadIdx.x; i < n; i += 256) yr[i] = (bf16)(xr[i] * inv * w[i]);
}

// ---------------- generic bf16 MFMA GEMM: C = act(A @ W^T) ----------------
template<int ACT, typename OT>
__global__ __launch_bounds__(256) void gemm_mfma(const bf16* __restrict__ A,
                                                 const bf16* __restrict__ W,
                                                 const float* __restrict__ R,
                                                 OT* __restrict__ C,
                                                 int M, int N, int K) {
  __shared__ bf16 As[128 * 32];
  __shared__ bf16 Ws[128 * 32];
  int tid = threadIdx.x, lane = tid & 63, wave = tid >> 6;
  int bm = blockIdx.y * 128, bn = blockIdx.x * 128;
  const bf16* gA0 = A + (size_t)(bm + wave * 32 + (lane >> 2)) * K + (lane & 3) * 8;
  const bf16* gA1 = gA0 + (size_t)16 * K;
  const bf16* gW0 = W + (size_t)(bn + wave * 32 + (lane >> 2)) * K + (lane & 3) * 8;
  const bf16* gW1 = gW0 + (size_t)16 * K;
  bf16* lA0 = As + wave * 32 * 32;
  bf16* lA1 = lA0 + 16 * 32;
  bf16* lW0 = Ws + wave * 32 * 32;
  bf16* lW1 = lW0 + 16 * 32;
  int fr = lane & 15, fq = lane >> 4;
  int wm = wave >> 1, wn = wave & 1;
  const bf16* pA = As + (wm * 64 + fr) * 32 + fq * 8;
  const bf16* pW = Ws + (wn * 64 + fr) * 32 + fq * 8;
  f32x4 acc[4][4] = {};
  for (int k0 = 0; k0 < K; k0 += 32) {
    async_copy16(gA0, lA0);
    async_copy16(gA1, lA1);
    async_copy16(gW0, lW0);
    async_copy16(gW1, lW1);
    gA0 += 32; gA1 += 32; gW0 += 32; gW1 += 32;
    __syncthreads();
    bf16x8 af[4], bfr[4];
#pragma unroll
    for (int mi = 0; mi < 4; mi++) af[mi] = *(const bf16x8*)(pA + mi * 16 * 32);
#pragma unroll
    for (int ni = 0; ni < 4; ni++) bfr[ni] = *(const bf16x8*)(pW + ni * 16 * 32);
#pragma unroll
    for (int mi = 0; mi < 4; mi++)
#pragma unroll
      for (int ni = 0; ni < 4; ni++)
        acc[mi][ni] = __builtin_amdgcn_mfma_f32_16x16x32_bf16(af[mi], bfr[ni], acc[mi][ni], 0, 0, 0);
    __syncthreads();
  }
#pragma unroll
  for (int mi = 0; mi < 4; mi++) {
    int row = bm + wm * 64 + mi * 16 + fq * 4;
#pragma unroll
    for (int ni = 0; ni < 4; ni++) {
      int col = bn + wn * 64 + ni * 16 + fr;
      if (col < N) {
#pragma unroll
        for (int r = 0; r < 4; r++) {
          float v = acc[mi][ni][r];
          if (ACT == 1) v = v / (1.f + __expf(-v));
          if (R) v += R[(size_t)(row + r) * N + col];
          C[(size_t)(row + r) * N + col] = (OT)v;
        }
      }
    }
  }
}

// ---------------- split-K bf16 MFMA GEMM: P[ks] = A @ W^T (partial over K slice) ----------------
__global__ __launch_bounds__(256) void gemm_sk(const bf16* __restrict__ A,
                                               const bf16* __restrict__ W,
                                               float* __restrict__ P,
                                               int M, int N, int K, int kchunk) {
  __shared__ bf16 As[128 * 32];
  __shared__ bf16 Ws[128 * 32];
  int tid = threadIdx.x, lane = tid & 63, wave = tid >> 6;
  int bm = blockIdx.y * 128, bn = blockIdx.x * 128;
  int ks = blockIdx.z;
  int kbeg = ks * kchunk;
  const bf16* gA0 = A + (size_t)(bm + wave * 32 + (lane >> 2)) * K + kbeg + (lane & 3) * 8;
  const bf16* gA1 = gA0 + (size_t)16 * K;
  const bf16* gW0 = W + (size_t)(bn + wave * 32 + (lane >> 2)) * K + kbeg + (lane & 3) * 8;
  const bf16* gW1 = gW0 + (size_t)16 * K;
  bf16* lA0 = As + wave * 32 * 32;
  bf16* lA1 = lA0 + 16 * 32;
  bf16* lW0 = Ws + wave * 32 * 32;
  bf16* lW1 = lW0 + 16 * 32;
  int fr = lane & 15, fq = lane >> 4;
  int wm = wave >> 1, wn = wave & 1;
  const bf16* pA = As + (wm * 64 + fr) * 32 + fq * 8;
  const bf16* pW = Ws + (wn * 64 + fr) * 32 + fq * 8;
  f32x4 acc[4][4] = {};
  for (int k0 = 0; k0 < kchunk; k0 += 32) {
    async_copy16(gA0, lA0);
    async_copy16(gA1, lA1);
    async_copy16(gW0, lW0);
    async_copy16(gW1, lW1);
    gA0 += 32; gA1 += 32; gW0 += 32; gW1 += 32;
    __syncthreads();
    bf16x8 af[4], bfr[4];
#pragma unroll
    for (int mi = 0; mi < 4; mi++) af[mi] = *(const bf16x8*)(pA + mi * 16 * 32);
#pragma unroll
    for (int ni = 0; ni < 4; ni++) bfr[ni] = *(const bf16x8*)(pW + ni * 16 * 32);
#pragma unroll
    for (int mi = 0; mi < 4; mi++)
#pragma unroll
      for (int ni = 0; ni < 4; ni++)
        acc[mi][ni] = __builtin_amdgcn_mfma_f32_16x16x32_bf16(af[mi], bfr[ni], acc[mi][ni], 0, 0, 0);
    __syncthreads();
  }
  float* Pp = P + (size_t)ks * M * N;
#pragma unroll
  for (int mi = 0; mi < 4; mi++) {
    int row = bm + wm * 64 + mi * 16 + fq * 4;
#pragma unroll
    for (int ni = 0; ni < 4; ni++) {
      int col = bn + wn * 64 + ni * 16 + fr;
#pragma unroll
      for (int r = 0; r < 4; r++)
        Pp[(size_t)(row + r) * N + col] = acc[mi][ni][r];
    }
  }
}

// ---------------- reduce 2 partials + residual + layernorm -> x_out f32, h bf16 ----------------
__global__ __launch_bounds__(256) void reduce_ln2(const float* __restrict__ p0,
                                                  const float* __restrict__ p1,
                                                  const float* __restrict__ res,
                                                  const float* __restrict__ w,
                                                  const float* __restrict__ b,
                                                  float* __restrict__ xo,
                                                  bf16* __restrict__ ho) {
  __shared__ float buf[1024];
  __shared__ float sh[4];
  size_t o = (size_t)blockIdx.x * 1024;
  float s = 0.f, s2 = 0.f;
  for (int i = threadIdx.x; i < 1024; i += 256) {
    float v = p0[o + i] + p1[o + i] + res[o + i];
    buf[i] = v; s += v; s2 += v * v;
  }
  s  = blockReduceSum<4>(s,  sh);
  s2 = blockReduceSum<4>(s2, sh);
  float mean = s / 1024.f;
  float var  = s2 / 1024.f - mean * mean;
  float inv  = rsqrtf(var + 1e-5f);
  for (int i = threadIdx.x; i < 1024; i += 256) {
    float v = buf[i];
    xo[o + i] = v;
    ho[o + i] = (bf16)((v - mean) * inv * w[i] + b[i]);
  }
}

// ---------------- reduce 3 partials + residual -> out f32 ----------------
__global__ __launch_bounds__(256) void reduce_out3(const float* __restrict__ p0,
                                                   const float* __restrict__ p1,
                                                   const float* __restrict__ p2,
                                                   const float* __restrict__ res,
                                                   float* __restrict__ out) {
  int i = (blockIdx.x * 256 + threadIdx.x) * 4;
  f32x4 v = *(const f32x4*)(p0 + i);
  v += *(const f32x4*)(p1 + i);
  v += *(const f32x4*)(p2 + i);
  v += *(const f32x4*)(res + i);
  *(f32x4*)(out + i) = v;
}

// ---------------- reduce qkv partials + q/k rmsnorm + rope + gain -> bf16 ----------------
__global__ __launch_bounds__(256) void reduce_qkv(const float* __restrict__ P,
                                                  const float* __restrict__ q_gain,
                                                  bf16* __restrict__ q,
                                                  bf16* __restrict__ k,
                                                  bf16* __restrict__ v) {
  __shared__ float buf[1536];
  size_t row = blockIdx.x;
  size_t o = row * 1536;
  const float* p0 = P + o;
  const float* p1 = P + (size_t)ROWS * 1536 + o;
  int tid = threadIdx.x;
  for (int i = tid; i < 384; i += 256) {
    f32x4 a = *(const f32x4*)(p0 + i * 4);
    f32x4 c = *(const f32x4*)(p1 + i * 4);
    *(f32x4*)(buf + i * 4) = a + c;
  }
  __syncthreads();
  int lane = tid & 63, w = tid >> 6;
  int s = (int)(row & (S_ - 1));
  // rope coeffs (valid for lane<16)
  int ri = lane & 7;
  float rinv = __expf(-(float)ri * (0.125f * 9.210340371976184f)); // 10000^(-i/8)
  float ang = (float)s * rinv;
  float cs = cosf(ang), sn = sinf(ang);
#pragma unroll
  for (int j = 0; j < 6; j++) {
    int hh = w * 6 + j;
    float val = buf[hh * 64 + lane];
    if (hh < 20) {
      float ss = val * val;
#pragma unroll
      for (int off = 32; off > 0; off >>= 1) ss += __shfl_xor(ss, off, 64);
      val *= rsqrtf(ss / 64.f + 1.1920929e-7f);
      float other = __shfl_xor(val, 8, 64);
      float res = val;
      if (lane < RD) res = (lane < 8) ? (val * cs + other * sn) : (val * cs - other * sn);
      if (hh < 16) {
        res *= q_gain[hh];
        q[row * (HATT * HD) + hh * HD + lane] = (bf16)res;
      } else {
        k[row * (KVH * HD) + (hh - 16) * HD + lane] = (bf16)res;
      }
    } else {
      v[row * (KVH * HD) + (hh - 20) * HD + lane] = (bf16)val;
    }
  }
}

// ---------------- in_proj GEMM: writes Zt/Xt transposed + compact bcdt ----------------
__global__ __launch_bounds__(256) void gemm_inproj(const bf16* __restrict__ A,
                                                   const bf16* __restrict__ W,
                                                   bf16* __restrict__ zt,
                                                   bf16* __restrict__ xt,
                                                   bf16* __restrict__ bcdt) {
  const int K = 1024;
  __shared__ bf16 As[128 * 32];
  __shared__ bf16 Ws[128 * 32];
  int tid = threadIdx.x, lane = tid & 63, wave = tid >> 6;
  int bm = blockIdx.y * 128, bn = blockIdx.x * 128;
  const bf16* gA0 = A + (size_t)(bm + wave * 32 + (lane >> 2)) * K + (lane & 3) * 8;
  const bf16* gA1 = gA0 + (size_t)16 * K;
  const bf16* gW0 = W + (size_t)(bn + wave * 32 + (lane >> 2)) * K + (lane & 3) * 8;
  const bf16* gW1 = gW0 + (size_t)16 * K;
  bf16* lA0 = As + wave * 32 * 32;
  bf16* lA1 = lA0 + 16 * 32;
  bf16* lW0 = Ws + wave * 32 * 32;
  bf16* lW1 = lW0 + 16 * 32;
  int fr = lane & 15, fq = lane >> 4;
  int wm = wave >> 1, wn = wave & 1;
  const bf16* pA = As + (wm * 64 + fr) * 32 + fq * 8;
  const bf16* pW = Ws + (wn * 64 + fr) * 32 + fq * 8;
  f32x4 acc[4][4] = {};
  for (int k0 = 0; k0 < K; k0 += 32) {
    async_copy16(gA0, lA0);
    async_copy16(gA1, lA1);
    async_copy16(gW0, lW0);
    async_copy16(gW1, lW1);
    gA0 += 32; gA1 += 32; gW0 += 32; gW1 += 32;
    __syncthreads();
    bf16x8 af[4], bfr[4];
#pragma unroll
    for (int mi = 0; mi < 4; mi++) af[mi] = *(const bf16x8*)(pA + mi * 16 * 32);
#pragma unroll
    for (int ni = 0; ni < 4; ni++) bfr[ni] = *(const bf16x8*)(pW + ni * 16 * 32);
#pragma unroll
    for (int mi = 0; mi < 4; mi++)
#pragma unroll
      for (int ni = 0; ni < 4; ni++)
        acc[mi][ni] = __builtin_amdgcn_mfma_f32_16x16x32_bf16(af[mi], bfr[ni], acc[mi][ni], 0, 0, 0);
    __syncthreads();
  }
#pragma unroll
  for (int mi = 0; mi < 4; mi++) {
    int row0m = bm + wm * 64 + mi * 16 + fq * 4;
    int b = row0m >> 11, sg = row0m & 2047;
#pragma unroll
    for (int ni = 0; ni < 4; ni++) {
      int col = bn + wn * 64 + ni * 16 + fr;
      bf16x4 o;
#pragma unroll
      for (int r = 0; r < 4; r++) o[r] = (bf16)acc[mi][ni][r];
      if (col < 2048) {
        *(bf16x4*)(zt + ((size_t)(b * NH + (col >> 6)) * HD + (col & 63)) * S_ + sg) = o;
      } else if (col < 4096) {
        int xc = col - 2048;
        *(bf16x4*)(xt + ((size_t)(b * NH + (xc >> 6)) * HD + (xc & 63)) * S_ + sg) = o;
      } else if (col < 4384) {
#pragma unroll
        for (int r = 0; r < 4; r++)
          bcdt[(size_t)(row0m + r) * 288 + (col - 4096)] = o[r];
      }
    }
  }
}

// ---------------- generic 64x64 tiled transpose (bf16), out row stride 2048 ----------------
__global__ __launch_bounds__(256) void t64(const bf16* __restrict__ in, bf16* __restrict__ out,
                                           int istr, size_t io, size_t oo, int n_nt) {
  __shared__ bf16 T[64 * 72];
  int bid = blockIdx.x;
  int st = bid & 31;
  int nt = (bid >> 5) % n_nt;
  int outer = bid / (32 * n_nt);
  const bf16* ip = in + outer * io + (size_t)st * 64 * istr + nt * 64;
  int tid = threadIdx.x;
#pragma unroll
  for (int i = 0; i < 2; i++) {
    int cid = tid + i * 256; int s = cid >> 3, pc = (cid & 7) * 8;
    *(bf16x8*)(T + s * 72 + pc) = *(const bf16x8*)(ip + (size_t)s * istr + pc);
  }
  __syncthreads();
  bf16* op = out + outer * oo + (size_t)nt * 64 * 2048 + st * 64;
#pragma unroll
  for (int i = 0; i < 2; i++) {
    int cid = tid + i * 256; int p = cid >> 3, sc = (cid & 7) * 8;
    bf16x8 o;
#pragma unroll
    for (int j = 0; j < 8; j++) o[j] = T[(sc + j) * 72 + p];
    *(bf16x8*)(op + (size_t)p * 2048 + sc) = o;
  }
}

// ---------------- SSD prep: dt softplus, per-chunk cumsum, decay factors ----------------
__global__ __launch_bounds__(64) void ssd_prep(const bf16* __restrict__ bcdt,
                                               const float* __restrict__ dt_bias,
                                               const float* __restrict__ A_log,
                                               float* __restrict__ dt_c,
                                               float* __restrict__ ddc,
                                               float* __restrict__ ac_c,
                                               float* __restrict__ T_out) {
  int bid = blockIdx.x;
  int c = bid % NC, hh = (bid / NC) % NH, b = bid / (NC * NH);
  int l = threadIdx.x;
  size_t row = (size_t)b * S_ + c * 64 + l;
  float raw = (float)bcdt[row * 288 + 256 + hh] + dt_bias[hh];
  float dtv = (raw > 20.f) ? raw : log1pf(__expf(raw));
  float a = -__expf(A_log[hh]) * dtv;
  float ps = a;
#pragma unroll
  for (int off = 1; off < 64; off <<= 1) {
    float t = __shfl_up(ps, off, 64);
    if (l >= off) ps += t;
  }
  float a63 = __shfl(ps, 63, 64);
  size_t o = ((size_t)b * NH + hh) * S_ + c * 64 + l;
  dt_c[o] = dtv;
  ac_c[o] = ps;
  ddc[o] = __expf(a63 - ps) * dtv;
  if (l == 63) T_out[(b * NH + hh) * NC + c] = ps;
}

// ---------------- B/C rmsnorm (bf16 out) ----------------
__global__ __launch_bounds__(128) void bc_norm(const bf16* __restrict__ bcdt,
                                               const float* __restrict__ Bw,
                                               const float* __restrict__ Cw,
                                               bf16* __restrict__ Bn,
                                               bf16* __restrict__ Cn) {
  __shared__ float shb[2], shc[2];
  size_t row = blockIdx.x;
  int i = threadIdx.x;
  float bv = (float)bcdt[row * 288 + i];
  float cv = (float)bcdt[row * 288 + 128 + i];
  float sb = waveReduceSum(bv * bv);
  float sc = waveReduceSum(cv * cv);
  int lane = threadIdx.x & 63, wid = threadIdx.x >> 6;
  if (lane == 0) { shb[wid] = sb; shc[wid] = sc; }
  __syncthreads();
  float tb = shb[0] + shb[1];
  float tc = shc[0] + shc[1];
  Bn[row * DS + i] = (bf16)(bv * rsqrtf(tb / DS + 1e-5f) * Bw[i]);
  Cn[row * DS + i] = (bf16)(cv * rsqrtf(tc / DS + 1e-5f) * Cw[i]);
}

// ---------------- chunk states via MFMA ----------------
__global__ __launch_bounds__(256) void ssd_states(const bf16* __restrict__ Xt,
                                                  const bf16* __restrict__ Btr,
                                                  const float* __restrict__ ddc,
                                                  float* __restrict__ states) {
  __shared__ bf16 Xs[64 * 72];    // [p][s]
  __shared__ bf16 Bs[128 * 72];   // [n][s]
  int bid = blockIdx.x;           // (b*NC + c)*NH + h
  int h = bid % NH;
  int c = (bid / NH) % NC;
  int b = bid / (NH * NC);
  int tid = threadIdx.x, lane = tid & 63, w = tid >> 6;
  int fr = lane & 15, fq = lane >> 4;
  const size_t xbase = (size_t)(b * NH + h) * HD * S_ + c * 64;
  const size_t dbase = (size_t)(b * NH + h) * S_ + c * 64;
#pragma unroll
  for (int i = 0; i < 2; i++) {
    int cid = tid + i * 256; int p = cid >> 3, sc = (cid & 7) * 8;
    bf16x8 xv = *(const bf16x8*)(Xt + xbase + (size_t)p * S_ + sc);
    f32x4 d0 = *(const f32x4*)(ddc + dbase + sc);
    f32x4 d1 = *(const f32x4*)(ddc + dbase + sc + 4);
    bf16x8 o;
#pragma unroll
    for (int j = 0; j < 4; j++) { o[j] = (bf16)((float)xv[j] * d0[j]); o[4 + j] = (bf16)((float)xv[4 + j] * d1[j]); }
    *(bf16x8*)(Xs + p * 72 + sc) = o;
  }
  const size_t bbase = (size_t)b * 128 * S_ + c * 64;
#pragma unroll
  for (int i = 0; i < 4; i++) {
    int cid = tid + i * 256; int n = cid >> 3, sc = (cid & 7) * 8;
    *(bf16x8*)(Bs + n * 72 + sc) = *(const bf16x8*)(Btr + bbase + (size_t)n * S_ + sc);
  }
  __syncthreads();
  f32x4 acc[4][2] = {};
#pragma unroll
  for (int ks = 0; ks < 2; ks++) {
    bf16x8 a[4], bb[2];
#pragma unroll
    for (int pt = 0; pt < 4; pt++) a[pt] = *(const bf16x8*)(Xs + (pt * 16 + fr) * 72 + ks * 32 + fq * 8);
#pragma unroll
    for (int n2 = 0; n2 < 2; n2++) bb[n2] = *(const bf16x8*)(Bs + ((2 * w + n2) * 16 + fr) * 72 + ks * 32 + fq * 8);
#pragma unroll
    for (int pt = 0; pt < 4; pt++)
#pragma unroll
      for (int n2 = 0; n2 < 2; n2++)
        acc[pt][n2] = __builtin_amdgcn_mfma_f32_16x16x32_bf16(a[pt], bb[n2], acc[pt][n2], 0, 0, 0);
  }
  float* outp = states + (size_t)bid * 8192;
#pragma unroll
  for (int pt = 0; pt < 4; pt++)
#pragma unroll
    for (int n2 = 0; n2 < 2; n2++) {
      int n = (2 * w + n2) * 16 + fr;
#pragma unroll
      for (int r = 0; r < 4; r++)
        outp[(size_t)(pt * 16 + fq * 4 + r) * 128 + n] = acc[pt][n2][r];
    }
}

// ---------------- inter-chunk scan (in place) ----------------
__global__ __launch_bounds__(256) void ssd_scan(float* __restrict__ states,
                                                const float* __restrict__ T) {
  __shared__ float eT[NC];
  int part = blockIdx.x & 7;
  int bh = blockIdx.x >> 3;
  int b = bh / NH, h = bh % NH;
  if (threadIdx.x < NC) eT[threadIdx.x] = __expf(T[(size_t)(b * NH + h) * NC + threadIdx.x]);
  __syncthreads();
  const size_t cstride = (size_t)NH * HD * DS;
  size_t base = ((size_t)b * NC * NH + h) * (HD * DS);
#pragma unroll
  for (int j = 0; j < 4; j++) {
    int e = part * 1024 + threadIdx.x + j * 256;
    float carry = 0.f;
    size_t idx = base + e;
    for (int c = 0; c < NC; c++) {
      float sv = states[idx];
      states[idx] = carry;
      carry = sv + eT[c] * carry;
      idx += cstride;
    }
  }
}

// ---------------- fused SSD output: Ydiag + Yoff + D-skip + gate (all MFMA) ----------------
__global__ __launch_bounds__(256) void ssd_out(const bf16* __restrict__ Cn,
                                               const bf16* __restrict__ Bn,
                                               const bf16* __restrict__ Xt,
                                               const bf16* __restrict__ Zt,
                                               const float* __restrict__ dt_c,
                                               const float* __restrict__ ac_c,
                                               const float* __restrict__ states,
                                               const float* __restrict__ Dp,
                                               bf16* __restrict__ ybf) {
  __shared__ bf16 Cs[64 * 136];
  __shared__ bf16 BNs[64 * 136];
  __shared__ bf16 Xs[64 * 72];
  __shared__ bf16 G[64 * 72];
  __shared__ float acs[64];
  int bid = blockIdx.x;
  int h = bid % NH;
  int c = (bid / NH) % NC;
  int b = bid / (NH * NC);
  int tid = threadIdx.x, lane = tid & 63, w = tid >> 6;
  int fr = lane & 15, fq = lane >> 4;
  size_t row0 = (size_t)b * S_ + c * 64;
  const size_t abase = (size_t)(b * NH + h) * S_ + c * 64;
  if (tid < 64) acs[tid] = ac_c[abase + tid];
#pragma unroll
  for (int i = 0; i < 4; i++) {
    int cid = tid + i * 256; int l = cid >> 4, nc = (cid & 15) * 8;
    float e = __expf(ac_c[abase + l]);
    bf16x8 cv = *(const bf16x8*)(Cn + (row0 + l) * DS + nc);
    bf16x8 o;
#pragma unroll
    for (int j = 0; j < 8; j++) o[j] = (bf16)((float)cv[j] * e);
    *(bf16x8*)(Cs + l * 136 + nc) = o;
    *(bf16x8*)(BNs + l * 136 + nc) = *(const bf16x8*)(Bn + (row0 + l) * DS + nc);
  }
  const size_t xbase = (size_t)(b * NH + h) * HD * S_ + c * 64;
#pragma unroll
  for (int i = 0; i < 2; i++) {
    int cid = tid + i * 256; int p = cid >> 3, sc = (cid & 7) * 8;
    bf16x8 xv = *(const bf16x8*)(Xt + xbase + (size_t)p * S_ + sc);
    f32x4 d0 = *(const f32x4*)(dt_c + abase + sc);
    f32x4 d1 = *(const f32x4*)(dt_c + abase + sc + 4);
    bf16x8 o;
#pragma unroll
    for (int j = 0; j < 4; j++) { o[j] = (bf16)((float)xv[j] * d0[j]); o[4 + j] = (bf16)((float)xv[4 + j] * d1[j]); }
    *(bf16x8*)(Xs + p * 72 + sc) = o;
  }
  __syncthreads();
  bf16x8 ca[4];
#pragma unroll
  for (int ks = 0; ks < 4; ks++) ca[ks] = *(const bf16x8*)(Cs + (w * 16 + fr) * 136 + ks * 32 + fq * 8);
  f32x4 cb[4] = {};
  for (int st = 0; st <= w; st++)
#pragma unroll
    for (int ks = 0; ks < 4; ks++)
      cb[st] = __builtin_amdgcn_mfma_f32_16x16x32_bf16(ca[ks],
                 *(const bf16x8*)(BNs + (st * 16 + fr) * 136 + ks * 32 + fq * 8), cb[st], 0, 0, 0);
#pragma unroll
  for (int st = 0; st < 4; st++) {
    float es = (st <= w) ? __expf(-acs[st * 16 + fr]) : 0.f;
#pragma unroll
    for (int r = 0; r < 4; r++) {
      int lloc = fq * 4 + r;
      float g = 0.f;
      if (st < w) g = cb[st][r] * es;
      else if (st == w) g = (lloc >= fr) ? cb[st][r] * es : 0.f;
      G[(w * 16 + lloc) * 72 + st * 16 + fr] = (bf16)g;
    }
  }
  f32x4 acc[4] = {};
  {
    bf16x8 ga0 = *(const bf16x8*)(G + (w * 16 + fr) * 72 + fq * 8);
    bf16x8 ga1 = *(const bf16x8*)(G + (w * 16 + fr) * 72 + 32 + fq * 8);
#pragma unroll
    for (int pt = 0; pt < 4; pt++) {
      acc[pt] = __builtin_amdgcn_mfma_f32_16x16x32_bf16(ga0,
                  *(const bf16x8*)(Xs + (pt * 16 + fr) * 72 + fq * 8), acc[pt], 0, 0, 0);
      acc[pt] = __builtin_amdgcn_mfma_f32_16x16x32_bf16(ga1,
                  *(const bf16x8*)(Xs + (pt * 16 + fr) * 72 + 32 + fq * 8), acc[pt], 0, 0, 0);
    }
  }
  __syncthreads();
  const float* stp = states + (size_t)bid * 8192;
#pragma unroll
  for (int i = 0; i < 4; i++) {
    int cid = tid + i * 256; int p = cid >> 4, nc = (cid & 15) * 8;
    f32x4 s0 = *(const f32x4*)(stp + (size_t)p * 128 + nc);
    f32x4 s1 = *(const f32x4*)(stp + (size_t)p * 128 + nc + 4);
    bf16x8 o;
#pragma unroll
    for (int j = 0; j < 4; j++) { o[j] = (bf16)s0[j]; o[4 + j] = (bf16)s1[j]; }
    *(bf16x8*)(BNs + p * 136 + nc) = o;
  }
  __syncthreads();
#pragma unroll
  for (int pt = 0; pt < 4; pt++)
#pragma unroll
    for (int ks = 0; ks < 4; ks++)
      acc[pt] = __builtin_amdgcn_mfma_f32_16x16x32_bf16(ca[ks],
                  *(const bf16x8*)(BNs + (pt * 16 + fr) * 136 + ks * 32 + fq * 8), acc[pt], 0, 0, 0);
  float dph = Dp[h];
#pragma unroll
  for (int pt = 0; pt < 4; pt++) {
    int p = pt * 16 + fr;
    size_t tb = (xbase + (size_t)p * S_) + w * 16 + fq * 4;
    bf16x4 xs4 = *(const bf16x4*)(Xt + tb);
    bf16x4 z4  = *(const bf16x4*)(Zt + tb);
#pragma unroll
    for (int r = 0; r < 4; r++) {
      int l = w * 16 + fq * 4 + r;
      float yv = acc[pt][r] + (float)xs4[r] * dph;
      float z = (float)z4[r];
      yv *= z / (1.f + __expf(-z));
      ybf[((row0 + l) * NH + h) * HD + p] = (bf16)yv;
    }
  }
}

// ---------------- MFMA flash attention (bf16 in, V pre-transposed) ----------------
__global__ __launch_bounds__(256) void attn_mfma(const bf16* __restrict__ q,
                                                 const bf16* __restrict__ k,
                                                 const bf16* __restrict__ vtr,
                                                 bf16* __restrict__ o) {
  __shared__ bf16 Qs[64 * 72];
  __shared__ bf16 Ks[64 * 72];
  __shared__ bf16 Vt[64 * 72];
  __shared__ bf16 Pl[4 * 16 * 72];
  int qt = (gridDim.x - 1) - blockIdx.x;
  int h = blockIdx.y, b = blockIdx.z;
  int kvh = h >> 2;
  int tid = threadIdx.x, lane = tid & 63, w = tid >> 6;
  int fr = lane & 15, fq = lane >> 4;
#pragma unroll
  for (int i = 0; i < 2; i++) {
    int cid = tid + i * 256; int r = cid >> 3, c8 = (cid & 7) * 8;
    *(bf16x8*)(Qs + r * 72 + c8) =
        *(const bf16x8*)(q + (size_t)(b * S_ + qt * 64 + r) * (HATT * HD) + h * HD + c8);
  }
  __syncthreads();
  bf16x8 bq0 = *(const bf16x8*)(Qs + (w * 16 + fr) * 72 + fq * 8);
  bf16x8 bq1 = *(const bf16x8*)(Qs + (w * 16 + fr) * 72 + 32 + fq * 8);
  int qpos = qt * 64 + w * 16 + fr;
  float m_run = -1e30f, lsum = 0.f;
  f32x4 yacc[4] = {};
  bf16* Plw = Pl + w * 16 * 72;
  for (int kt = 0; kt <= qt; kt++) {
    __syncthreads();
#pragma unroll
    for (int i = 0; i < 2; i++) {
      int cid = tid + i * 256; int r = cid >> 3, c8 = (cid & 7) * 8;
      *(bf16x8*)(Ks + r * 72 + c8) =
          *(const bf16x8*)(k + (size_t)(b * S_ + kt * 64 + r) * (KVH * HD) + kvh * HD + c8);
      *(bf16x8*)(Vt + r * 72 + c8) =
          *(const bf16x8*)(vtr + ((size_t)(b * KVH + kvh) * HD + r) * S_ + (size_t)kt * 64 + c8);
    }
    __syncthreads();
    f32x4 sacc[4] = {};
#pragma unroll
    for (int mi = 0; mi < 4; mi++) {
      bf16x8 ak0 = *(const bf16x8*)(Ks + (mi * 16 + fr) * 72 + fq * 8);
      bf16x8 ak1 = *(const bf16x8*)(Ks + (mi * 16 + fr) * 72 + 32 + fq * 8);
      sacc[mi] = __builtin_amdgcn_mfma_f32_16x16x32_bf16(ak0, bq0, sacc[mi], 0, 0, 0);
      sacc[mi] = __builtin_amdgcn_mfma_f32_16x16x32_bf16(ak1, bq1, sacc[mi], 0, 0, 0);
    }
    float lm = -1e30f;
    float sv[16];
#pragma unroll
    for (int mi = 0; mi < 4; mi++)
#pragma unroll
      for (int r = 0; r < 4; r++) {
        int kpos = kt * 64 + mi * 16 + fq * 4 + r;
        float s = sacc[mi][r] * 0.125f;
        if (kpos > qpos) s = -1e30f;
        sv[mi * 4 + r] = s;
        lm = fmaxf(lm, s);
      }
    lm = fmaxf(lm, __shfl_xor(lm, 16, 64));
    lm = fmaxf(lm, __shfl_xor(lm, 32, 64));
    float mnew = fmaxf(m_run, lm);
    float alpha = __expf(m_run - mnew);
    m_run = mnew;
    float ls = 0.f;
#pragma unroll
    for (int mi = 0; mi < 4; mi++) {
      bf16x4 pk;
#pragma unroll
      for (int r = 0; r < 4; r++) {
        float p = __expf(sv[mi * 4 + r] - mnew);
        ls += p;
        pk[r] = (bf16)p;
      }
      *(bf16x4*)(Plw + fr * 72 + mi * 16 + fq * 4) = pk;
    }
    ls += __shfl_xor(ls, 16, 64);
    ls += __shfl_xor(ls, 32, 64);
    lsum = lsum * alpha + ls;
#pragma unroll
    for (int pi = 0; pi < 4; pi++) yacc[pi] *= alpha;
    bf16x8 bp0 = *(const bf16x8*)(Plw + fr * 72 + fq * 8);
    bf16x8 bp1 = *(const bf16x8*)(Plw + fr * 72 + 32 + fq * 8);
#pragma unroll
    for (int pi = 0; pi < 4; pi++) {
      bf16x8 av0 = *(const bf16x8*)(Vt + (pi * 16 + fr) * 72 + fq * 8);
      bf16x8 av1 = *(const bf16x8*)(Vt + (pi * 16 + fr) * 72 + 32 + fq * 8);
      yacc[pi] = __builtin_amdgcn_mfma_f32_16x16x32_bf16(av0, bp0, yacc[pi], 0, 0, 0);
      yacc[pi] = __builtin_amdgcn_mfma_f32_16x16x32_bf16(av1, bp1, yacc[pi], 0, 0, 0);
    }
  }
  float inv = 1.f / lsum;
  int l = w * 16 + fr;
#pragma unroll
  for (int pi = 0; pi < 4; pi++)
#pragma unroll
    for (int r = 0; r < 4; r++) {
      int p = pi * 16 + fq * 4 + r;
      o[(size_t)(b * S_ + qt * 64 + l) * (HATT * HD) + h * HD + p] = (bf16)(yacc[pi][r] * inv);
    }
}

// ---------------- workspace layout (byte offsets) ----------------
constexpr size_t OFF_WIN  = 0;                   // bf16 4480x1024
constexpr size_t OFF_WOUT = 9175040;             // bf16 1024x2048
constexpr size_t OFF_WQKV = 13369344;            // bf16 1536x1024 (q|k|v rows)
constexpr size_t OFF_WCP  = 16515072;            // bf16 1024x1024
constexpr size_t OFF_WFC  = 18612224;            // bf16 3072x1024
constexpr size_t OFF_WPR  = 24903680;            // bf16 1024x3072
constexpr size_t OFF_HBF  = 31195136;            // bf16 4096x1024
constexpr size_t OFF_BCDT = 39583744;            // bf16 4096x288
constexpr size_t OFF_XT   = 41943040;            // bf16 [b][h][p][sg]
constexpr size_t OFF_ZT   = 58720256;            // bf16 [b][h][p][sg]
constexpr size_t OFF_DTC  = 75497472;            // f32 [b][h][sg]
constexpr size_t OFF_DDC  = 76546048;            // f32
constexpr size_t OFF_ACC  = 77594624;            // f32
constexpr size_t OFF_T    = 78643200;            // f32 2048
constexpr size_t OFF_BN   = 78651392;            // bf16 4096x128
constexpr size_t OFF_CN   = 79699968;            // bf16 4096x128
constexpr size_t OFF_BTR  = 80748544;            // bf16 [b][n][sg]
constexpr size_t OFF_ST   = 81797120;            // f32 2048x64x128 (67.1 MB)
constexpr size_t OFF_YBF  = 148905984;           // bf16 4096x2048
constexpr size_t OFF_X1   = 165683200;           // f32 4096x1024 (end 182,460,416)
// aliases (st region dead after ssd_out; Xt/Zt dead after ssd_out; ybf dead after out_proj)
constexpr size_t OFF_P    = OFF_ST;              // f32 split-K partials (up to 50.3 MB)
constexpr size_t OFF_QB   = OFF_ST + 50331648;   // bf16 4096x1024
constexpr size_t OFF_KB   = OFF_ST + 58720256;   // bf16 4096x256
constexpr size_t OFF_VB   = OFF_ST + 60817408;   // bf16 4096x256
constexpr size_t OFF_VTR  = OFF_ST + 62914560;   // bf16 [b][kvh][p][sg] (end 146,821,120)
constexpr size_t OFF_Y2   = OFF_XT;              // bf16 4096x1024
constexpr size_t OFF_X2   = 50331648;            // f32 4096x1024 (in dead Xt/Zt space)
constexpr size_t OFF_MLPB = OFF_ST + 50331648 + 25165824; // unused slot guard
constexpr size_t OFF_MLP  = 132128768;           // bf16 4096x3072 (over qb..vtr + ybf, all dead)

extern "C" void kernel_launch(void* const* d_in, const int* in_sizes, int n_in,
                              void* d_out, int out_size, void* d_ws, size_t ws_size,
                              hipStream_t stream) {
  (void)in_sizes; (void)n_in; (void)out_size; (void)ws_size;
  const float* x        = (const float*)d_in[0];
  const float* mnorm_w  = (const float*)d_in[1];
  const float* in_w     = (const float*)d_in[2];
  const float* out_w    = (const float*)d_in[3];
  const float* Dp       = (const float*)d_in[4];
  const float* dt_bias  = (const float*)d_in[5];
  const float* A_log    = (const float*)d_in[6];
  const float* Bn_w     = (const float*)d_in[7];
  const float* Cn_w     = (const float*)d_in[8];
  const float* ln1_w    = (const float*)d_in[9];
  const float* ln1_b    = (const float*)d_in[10];
  const float* cq_w     = (const float*)d_in[11];
  const float* ck_w     = (const float*)d_in[12];
  const float* cv_w     = (const float*)d_in[13];
  const float* cproj_w  = (const float*)d_in[14];
  const float* q_gain   = (const float*)d_in[15];
  const float* ln2_w    = (const float*)d_in[16];
  const float* ln2_b    = (const float*)d_in[17];
  const float* fc_w     = (const float*)d_in[18];
  const float* proj_w   = (const float*)d_in[19];
  float* out = (float*)d_out;
  char* W8 = (char*)d_ws;

  bf16* w_in   = (bf16*)(W8 + OFF_WIN);
  bf16* w_out  = (bf16*)(W8 + OFF_WOUT);
  bf16* w_qkv  = (bf16*)(W8 + OFF_WQKV);
  bf16* w_cp   = (bf16*)(W8 + OFF_WCP);
  bf16* w_fc   = (bf16*)(W8 + OFF_WFC);
  bf16* w_pr   = (bf16*)(W8 + OFF_WPR);
  bf16* h_bf   = (bf16*)(W8 + OFF_HBF);
  bf16* bcdt   = (bf16*)(W8 + OFF_BCDT);
  bf16* Xt     = (bf16*)(W8 + OFF_XT);
  bf16* Zt     = (bf16*)(W8 + OFF_ZT);
  float* dt_c  = (float*)(W8 + OFF_DTC);
  float* ddc   = (float*)(W8 + OFF_DDC);
  float* ac_c  = (float*)(W8 + OFF_ACC);
  float* Tb    = (float*)(W8 + OFF_T);
  bf16* Bn     = (bf16*)(W8 + OFF_BN);
  bf16* Cn     = (bf16*)(W8 + OFF_CN);
  bf16* Btr    = (bf16*)(W8 + OFF_BTR);
  float* st    = (float*)(W8 + OFF_ST);
  bf16* ybf    = (bf16*)(W8 + OFF_YBF);
  float* x1    = (float*)(W8 + OFF_X1);
  float* Pbuf  = (float*)(W8 + OFF_P);
  bf16* qbf    = (bf16*)(W8 + OFF_QB);
  bf16* kbf    = (bf16*)(W8 + OFF_KB);
  bf16* vbf    = (bf16*)(W8 + OFF_VB);
  bf16* vtr    = (bf16*)(W8 + OFF_VTR);
  bf16* y2     = (bf16*)(W8 + OFF_Y2);
  float* x2    = (float*)(W8 + OFF_X2);
  bf16* mlp    = (bf16*)(W8 + OFF_MLP);

  // ---- weight casts (single launch; q/k/v cast into adjacent rows of w_qkv) ----
  CastArgs ca;
  ca.seg[0] = { in_w,    w_in,            4489216, 4587520, 0     };
  ca.seg[1] = { out_w,   w_out,           2097152, 2097152, 4480  };
  ca.seg[2] = { cq_w,    w_qkv,           1048576, 1048576, 6528  };
  ca.seg[3] = { ck_w,    w_qkv + 1048576,  262144,  262144, 7552  };
  ca.seg[4] = { cv_w,    w_qkv + 1310720,  262144,  262144, 7808  };
  ca.seg[5] = { cproj_w, w_cp,            1048576, 1048576, 8064  };
  ca.seg[6] = { fc_w,    w_fc,            3145728, 3145728, 9088  };
  ca.seg[7] = { proj_w,  w_pr,            3145728, 3145728, 12160 };
  castw_all<<<15232, 256, 0, stream>>>(ca);

  const size_t PS = (size_t)ROWS * 1024;   // partial stride for N=1024 GEMMs

  // ---- mamba block ----
  rmsnorm_k<<<ROWS, 256, 0, stream>>>(x, mnorm_w, h_bf, D_);
  gemm_inproj<<<dim3(35, 32), 256, 0, stream>>>(h_bf, w_in, Zt, Xt, bcdt);
  ssd_prep<<<B_ * NH * NC, 64, 0, stream>>>(bcdt, dt_bias, A_log, dt_c, ddc, ac_c, Tb);
  bc_norm<<<ROWS, 128, 0, stream>>>(bcdt, Bn_w, Cn_w, Bn, Cn);
  t64<<<2 * 2 * 32, 256, 0, stream>>>(Bn, Btr, 128, (size_t)2048 * 128, (size_t)128 * 2048, 2);
  ssd_states<<<B_ * NC * NH, 256, 0, stream>>>(Xt, Btr, ddc, st);
  ssd_scan<<<B_ * NH * 8, 256, 0, stream>>>(st, Tb);
  ssd_out<<<B_ * NC * NH, 256, 0, stream>>>(Cn, Bn, Xt, Zt, dt_c, ac_c, st, Dp, ybf);
  // out_proj: split-K=2 then fused reduce+residual+LN1
  gemm_sk<<<dim3(8, 32, 2), 256, 0, stream>>>(ybf, w_out, Pbuf, ROWS, D_, DI, 1024);
  reduce_ln2<<<ROWS, 256, 0, stream>>>(Pbuf, Pbuf + PS, x, ln1_w, ln1_b, x1, h_bf);

  // ---- attention block ----
  gemm_sk<<<dim3(12, 32, 2), 256, 0, stream>>>(h_bf, w_qkv, Pbuf, ROWS, 1536, D_, 512);
  reduce_qkv<<<ROWS, 256, 0, stream>>>(Pbuf, q_gain, qbf, kbf, vbf);
  t64<<<2 * 4 * 32, 256, 0, stream>>>(vbf, vtr, 256, (size_t)2048 * 256, (size_t)256 * 2048, 4);
  attn_mfma<<<dim3(S_ / 64, HATT, B_), 256, 0, stream>>>(qbf, kbf, vtr, y2);
  gemm_sk<<<dim3(8, 32, 2), 256, 0, stream>>>(y2, w_cp, Pbuf, ROWS, D_, D_, 512);
  reduce_ln2<<<ROWS, 256, 0, stream>>>(Pbuf, Pbuf + PS, x1, ln2_w, ln2_b, x2, h_bf);

  // ---- MLP ----
  gemm_mfma<1, bf16><<<dim3(24, 32), 256, 0, stream>>>(h_bf, w_fc, nullptr, mlp, ROWS, MLP, D_);
  gemm_sk<<<dim3(8, 32, 3), 256, 0, stream>>>(mlp, w_pr, Pbuf, ROWS, D_, MLP, 1024);
  reduce_out3<<<ROWS, 256, 0, stream>>>(Pbuf, Pbuf + PS, Pbuf + 2 * PS, x2, out);
}